// Round 4
// baseline (465.881 us; speedup 1.0000x reference)
//
#include <hip/hip_runtime.h>
#include <hip/hip_bf16.h>

#define MODEL 2048
#define NHEAD 16
#define HDIM  128
#define BB    2
#define LL    2048
#define N1    (3*MODEL)      // 6144
#define MTOT  (BB*LL)        // 4096

typedef __hip_bfloat16 bf16;
typedef __attribute__((ext_vector_type(8))) short bf16x8;
typedef __attribute__((ext_vector_type(4))) float f32x4;

static __device__ __forceinline__ f32x4 mfma16(bf16x8 a, bf16x8 b, f32x4 c) {
  return __builtin_amdgcn_mfma_f32_16x16x32_bf16(a, b, c, 0, 0, 0);
}

// async global->LDS DMA, 16B per lane; LDS base wave-uniform, dest linear
static __device__ __forceinline__ void gl_lds16(const void* g, void* l) {
  __builtin_amdgcn_global_load_lds(
      (const __attribute__((address_space(1))) unsigned int*)g,
      (__attribute__((address_space(3))) unsigned int*)l, 16, 0, 0);
}

// ---------------- prep: f32 -> bf16 (vectorized x4) ----------------
__global__ void k_cvt(const float* __restrict__ in, bf16* __restrict__ out, int n4) {
  int i = blockIdx.x * blockDim.x + threadIdx.x;
  if (i < n4) {
    float4 v = ((const float4*)in)[i];
    bf16* o = out + (size_t)i * 4;
    o[0] = __float2bfloat16(v.x);
    o[1] = __float2bfloat16(v.y);
    o[2] = __float2bfloat16(v.z);
    o[3] = __float2bfloat16(v.w);
  }
}

// ---------------- prep: transpose f32 [R][C] -> bf16 [C][R] ----------------
__global__ __launch_bounds__(256)
void k_transpose(const float* __restrict__ in, bf16* __restrict__ out, int R, int C) {
  __shared__ float t[32][33];
  const int c0 = blockIdx.x * 32, r0 = blockIdx.y * 32;
  const int tx = threadIdx.x & 31;
  const int ty = threadIdx.x >> 5;   // 0..7
#pragma unroll
  for (int i = 0; i < 4; ++i)
    t[ty + 8*i][tx] = in[(size_t)(r0 + ty + 8*i) * C + c0 + tx];
  __syncthreads();
#pragma unroll
  for (int i = 0; i < 4; ++i)
    out[(size_t)(c0 + ty + 8*i) * R + r0 + tx] = __float2bfloat16(t[tx][ty + 8*i]);
}

// ============ 256x256 8-phase GEMM (HK schedule in plain HIP) ============
// C = A[M][K] * BT[N][K]^T. BK=64 per K-tile, 2 K-tiles per iter, 8 phases.
// LDS 128KB dynamic: A [2buf][2half][128][64] @0, B same @65536.
// 128B-row swizzle (G4): LDS in-row byte col' = col ^ ((row&7)<<4); staged via
// lane-permuted global source l2 = lane ^ ((lane>>3)&7) with linear gl_lds dest.
// EPI==1: RoPE + scatter Q/K row-major + V^T ; EPI==2: bias + f32 out.

#define BARRIER __builtin_amdgcn_s_barrier()
#define WAIT_LGKM0 { asm volatile("s_waitcnt lgkmcnt(0)" ::: "memory"); __builtin_amdgcn_sched_barrier(0); }
#define WAIT_VM4   { asm volatile("s_waitcnt vmcnt(4)"   ::: "memory"); __builtin_amdgcn_sched_barrier(0); }
#define PRIO1 __builtin_amdgcn_s_setprio(1)
#define PRIO0 __builtin_amdgcn_s_setprio(0)

#define RDA(P, MF0) \
  _Pragma("unroll") for (int q = 0; q < 4; ++q) { \
    aF[(MF0)+q][0] = *(const bf16x8*)(smem + (P) + aRow + ((MF0)+q)*2048 + c0); \
    aF[(MF0)+q][1] = *(const bf16x8*)(smem + (P) + aRow + ((MF0)+q)*2048 + c1); }
#define RDB(P, NF0) \
  _Pragma("unroll") for (int q = 0; q < 2; ++q) { \
    bF[(NF0)+q][0] = *(const bf16x8*)(smem + (P) + bRow + ((NF0)+q)*2048 + c0); \
    bF[(NF0)+q][1] = *(const bf16x8*)(smem + (P) + bRow + ((NF0)+q)*2048 + c1); }

#define MMQ(MF0, NF0) \
  _Pragma("unroll") for (int m_ = (MF0); m_ < (MF0)+4; ++m_) \
  _Pragma("unroll") for (int n_ = (NF0); n_ < (NF0)+2; ++n_) { \
    acc[m_][n_] = mfma16(aF[m_][0], bF[n_][0], acc[m_][n_]); \
    acc[m_][n_] = mfma16(aF[m_][1], bF[n_][1], acc[m_][n_]); }

#define STAGE_A(D, H, KT) { \
    const bf16* g_ = AsrcL + (size_t)(H)*128*Kd + (size_t)(KT)*64; \
    gl_lds16(g_,                  smem + ldsAw + (D)*32768 + (H)*16384); \
    gl_lds16(g_ + (size_t)64*Kd,  smem + ldsAw + (D)*32768 + (H)*16384 + 8192); }
#define STAGE_B(D, H, KT) { \
    const bf16* g_ = BsrcL + (size_t)(H)*128*Kd + (size_t)(KT)*64; \
    gl_lds16(g_,                  smem + ldsBw + (D)*32768 + (H)*16384); \
    gl_lds16(g_ + (size_t)64*Kd,  smem + ldsBw + (D)*32768 + (H)*16384 + 8192); }

template<int EPI>
__global__ __launch_bounds__(512, 2)
void k_gemm8(const bf16* __restrict__ A, const bf16* __restrict__ BT,
             int M, int N, int K,
             float* __restrict__ Cout, const float* __restrict__ bias,
             bf16* __restrict__ Qb, bf16* __restrict__ Kb, bf16* __restrict__ VTb,
             const float* __restrict__ cosT, const float* __restrict__ sinT)
{
  extern __shared__ char smem[];      // 131072 B
  const int Kd = K;
  const int tid = threadIdx.x;
  const int wid = tid >> 6, lane = tid & 63;
  const int wm = wid >> 2, wn = wid & 3;       // wave grid 2(M) x 4(N)
  const int lr = lane & 15, lkg = lane >> 4;
  const int m0 = blockIdx.y * 256, n0 = blockIdx.x * 256;

  // staging lane geometry: dest p=lane*16 needs global row lane>>3,
  // colbyte (lane&7)*16 ^ ((lane>>3 & 7)<<4)  ->  source col from l2
  const int srow = lane >> 3;                      // 0..7
  const int scol = ((lane ^ (lane >> 3)) & 7) * 8; // bf16 elems
  const bf16* AsrcL = A  + (size_t)(m0 + wid*8 + srow) * Kd + scol;
  const bf16* BsrcL = BT + (size_t)(n0 + wid*8 + srow) * Kd + scol;
  const int ldsAw = wid * 1024;
  const int ldsBw = 65536 + wid * 1024;

  // ds_read addressing: row base (no XOR) + per-half column XOR'd offsets
  const int swz = (lr & 7) << 4;
  const int c0 = (lkg * 16) ^ swz;         // k-half 0, stays within 0..127
  const int c1 = (lkg * 16 + 64) ^ swz;    // k-half 1
  const int aRow = wm*16384 + lr*128;
  const int bRow = 65536 + (wn >> 1)*16384 + ((wn & 1)*64 + lr)*128;

  const f32x4 vzero = {0.f, 0.f, 0.f, 0.f};
  f32x4 acc[8][4];
#pragma unroll
  for (int i = 0; i < 8; ++i)
#pragma unroll
    for (int j = 0; j < 4; ++j) acc[i][j] = vzero;
  bf16x8 aF[8][2], bF[4][2];

  const int nt = K >> 6;          // K-tiles of 64
  const int nIter = nt >> 1;

  // prologue: tile0 (A+B) + tile1 (A)
  STAGE_A(0,0,0) STAGE_A(0,1,0) STAGE_B(0,0,0) STAGE_B(0,1,0)
  STAGE_A(1,0,1) STAGE_A(1,1,1)
  WAIT_VM4; BARRIER;

  for (int i = 0; i < nIter; ++i) {
    const int to = 2*i + 1;
    int t2 = 2*i + 2; if (t2 >= nt) t2 = nt - 1;   // clamped: data unused
    int t3 = 2*i + 3; if (t3 >= nt) t3 = nt - 1;
    // ---- tile e = 2i from buf0 ----
    RDA(0,0) RDB(0,0) STAGE_B(1,0,to)                       // ph1
    BARRIER; WAIT_LGKM0; PRIO1; MMQ(0,0); PRIO0; BARRIER;
    RDA(0,4) RDB(0,2) STAGE_B(1,1,to)                       // ph2
    BARRIER; WAIT_LGKM0; PRIO1; MMQ(4,2); PRIO0; BARRIER;
    STAGE_A(0,0,t2)                                         // ph3
    BARRIER; PRIO1; MMQ(0,2); PRIO0; BARRIER;
    STAGE_A(0,1,t2)                                         // ph4
    BARRIER; PRIO1; MMQ(4,0); PRIO0; WAIT_VM4; BARRIER;
    // ---- tile o = 2i+1 from buf1 ----
    RDA(32768,0) RDB(32768,0) STAGE_B(0,0,t2)               // ph5
    BARRIER; WAIT_LGKM0; PRIO1; MMQ(0,0); PRIO0; BARRIER;
    RDA(32768,4) RDB(32768,2) STAGE_B(0,1,t2)               // ph6
    BARRIER; WAIT_LGKM0; PRIO1; MMQ(4,2); PRIO0; BARRIER;
    STAGE_A(1,0,t3)                                         // ph7
    BARRIER; PRIO1; MMQ(0,2); PRIO0; BARRIER;
    STAGE_A(1,1,t3)                                         // ph8
    BARRIER; PRIO1; MMQ(4,0); PRIO0; WAIT_VM4; BARRIER;
  }

  if constexpr (EPI == 1) {
    const float inv_sqrt_d = 0.08838834764831845f;  // 1/sqrt(128)
#pragma unroll
    for (int nf = 0; nf < 4; ++nf) {
      const int gcb = n0 + wn*64 + nf*16;           // wave-uniform, mult of 16
      const int section = gcb >> 11;                // 0=q 1=k 2=v
      const int cc = (gcb & 2047) + lr;
      const int h = cc >> 7, d = cc & 127;
#pragma unroll
      for (int mf = 0; mf < 8; ++mf) {
#pragma unroll
        for (int reg = 0; reg < 4; ++reg) {
          const int grow = m0 + wm*128 + mf*16 + lkg*4 + reg;
          const int bidx = grow >> 11, lseq = grow & 2047;
          float val = acc[mf][nf][reg];
          if (section < 2) {
            float p = __shfl_xor(val, 1);           // RoPE pair partner
            const int fi = d >> 1;
            float cv = cosT[(size_t)lseq * 64 + fi];
            float sv = sinT[(size_t)lseq * 64 + fi];
            float r = (d & 1) ? fmaf(p, sv, val * cv)
                              : fmaf(val, cv, -p * sv);
            if (section == 0) {
              r *= inv_sqrt_d;
              Qb[((size_t)(bidx*NHEAD + h) * LL + lseq) * HDIM + d] = __float2bfloat16(r);
            } else {
              Kb[((size_t)(bidx*NHEAD + h) * LL + lseq) * HDIM + d] = __float2bfloat16(r);
            }
          } else {
            VTb[((size_t)(bidx*NHEAD + h) * HDIM + d) * LL + lseq] = __float2bfloat16(val);
          }
        }
      }
    }
  } else {
#pragma unroll
    for (int nf = 0; nf < 4; ++nf) {
      const int gcol = n0 + wn*64 + nf*16 + lr;
      const float bv = bias[gcol];
#pragma unroll
      for (int mf = 0; mf < 8; ++mf) {
#pragma unroll
        for (int reg = 0; reg < 4; ++reg) {
          const int grow = m0 + wm*128 + mf*16 + lkg*4 + reg;
          Cout[(size_t)grow * N + gcol] = acc[mf][nf][reg] + bv;
        }
      }
    }
  }
}

// ---------------- flash attention (unchanged) ----------------
__global__ __launch_bounds__(256, 2)
void k_attn(const bf16* __restrict__ Qb, const bf16* __restrict__ Kb,
            const bf16* __restrict__ VTb, bf16* __restrict__ attnA)
{
  __shared__ bf16 Ks[64][136];
  __shared__ bf16 Vs[128][72];
  __shared__ bf16 Ps[4][32][72];

  const int bh  = blockIdx.y;
  const int qb  = (gridDim.x - 1) - blockIdx.x;
  const int tid = threadIdx.x;
  const int wid = tid >> 6, lane = tid & 63;
  const int lr  = lane & 15, lkg = lane >> 4;
  const int Q0  = qb * 128;
  const int q0w = Q0 + wid * 32;

  const bf16* Qh = Qb  + (size_t)bh * LL * HDIM;
  const bf16* Kh = Kb  + (size_t)bh * LL * HDIM;
  const bf16* Vh = VTb + (size_t)bh * HDIM * LL;

  const f32x4 vzero = {0.f, 0.f, 0.f, 0.f};
  bf16x8 qf[2][4];
#pragma unroll
  for (int qr = 0; qr < 2; ++qr)
#pragma unroll
    for (int kk = 0; kk < 4; ++kk)
      qf[qr][kk] = *(const bf16x8*)(Qh + (size_t)(q0w + qr*16 + lr) * HDIM + kk*32 + lkg*8);

  f32x4 oacc[2][8];
#pragma unroll
  for (int qr = 0; qr < 2; ++qr)
#pragma unroll
    for (int db = 0; db < 8; ++db) oacc[qr][db] = vzero;
  float mrow[2][4], lrow[2][4];
#pragma unroll
  for (int qr = 0; qr < 2; ++qr)
#pragma unroll
    for (int r = 0; r < 4; ++r) { mrow[qr][r] = -INFINITY; lrow[qr][r] = 0.f; }

  const int NT = Q0 / 64 + 2;
  bf16x8 kpre[4], vpre[4];
#pragma unroll
  for (int j = 0; j < 4; ++j) {
    const int c = j*256 + tid;
    kpre[j] = *(const bf16x8*)(Kh + (size_t)(c >> 4) * HDIM + (c & 15) * 8);
    vpre[j] = *(const bf16x8*)(Vh + (size_t)(c >> 3) * LL + (c & 7) * 8);
  }

  for (int kt = 0; kt < NT; ++kt) {
    const int kbase = kt * 64;
    __syncthreads();
#pragma unroll
    for (int j = 0; j < 4; ++j) {
      const int c = j*256 + tid;
      *(bf16x8*)&Ks[c >> 4][(c & 15) * 8] = kpre[j];
      *(bf16x8*)&Vs[c >> 3][(c & 7) * 8]  = vpre[j];
    }
    __syncthreads();
    if (kt + 1 < NT) {
#pragma unroll
      for (int j = 0; j < 4; ++j) {
        const int c = j*256 + tid;
        kpre[j] = *(const bf16x8*)(Kh + (size_t)((kt+1)*64 + (c >> 4)) * HDIM + (c & 15) * 8);
        vpre[j] = *(const bf16x8*)(Vh + (size_t)(c >> 3) * LL + (kt+1)*64 + (c & 7) * 8);
      }
    }
    if (kbase <= q0w + 31) {
      f32x4 s[2][4];
#pragma unroll
      for (int qr = 0; qr < 2; ++qr)
#pragma unroll
        for (int c = 0; c < 4; ++c) s[qr][c] = vzero;
#pragma unroll
      for (int c = 0; c < 4; ++c) {
        bf16x8 kf[4];
#pragma unroll
        for (int kk = 0; kk < 4; ++kk)
          kf[kk] = *(const bf16x8*)&Ks[c*16 + lr][kk*32 + lkg*8];
#pragma unroll
        for (int qr = 0; qr < 2; ++qr)
#pragma unroll
          for (int kk = 0; kk < 4; ++kk)
            s[qr][c] = mfma16(qf[qr][kk], kf[kk], s[qr][c]);
      }
#pragma unroll
      for (int qr = 0; qr < 2; ++qr) {
        float scl4[4];
#pragma unroll
        for (int reg = 0; reg < 4; ++reg) {
          const int row = q0w + qr*16 + lkg*4 + reg;
          float v0 = (kbase      + lr <= row) ? s[qr][0][reg] : -INFINITY;
          float v1 = (kbase + 16 + lr <= row) ? s[qr][1][reg] : -INFINITY;
          float v2 = (kbase + 32 + lr <= row) ? s[qr][2][reg] : -INFINITY;
          float v3 = (kbase + 48 + lr <= row) ? s[qr][3][reg] : -INFINITY;
          float tm = fmaxf(fmaxf(v0, v1), fmaxf(v2, v3));
          tm = fmaxf(tm, __shfl_xor(tm, 1));
          tm = fmaxf(tm, __shfl_xor(tm, 2));
          tm = fmaxf(tm, __shfl_xor(tm, 4));
          tm = fmaxf(tm, __shfl_xor(tm, 8));
          const float mnew = fmaxf(mrow[qr][reg], tm);
          const float scl  = __expf(mrow[qr][reg] - mnew);
          mrow[qr][reg] = mnew;
          float p0 = __expf(v0 - mnew);
          float p1 = __expf(v1 - mnew);
          float p2 = __expf(v2 - mnew);
          float p3 = __expf(v3 - mnew);
          float rs = (p0 + p1) + (p2 + p3);
          rs += __shfl_xor(rs, 1);
          rs += __shfl_xor(rs, 2);
          rs += __shfl_xor(rs, 4);
          rs += __shfl_xor(rs, 8);
          lrow[qr][reg] = lrow[qr][reg] * scl + rs;
          scl4[reg] = scl;
          const int prow = qr*16 + lkg*4 + reg;
          Ps[wid][prow][lr]      = __float2bfloat16(p0);
          Ps[wid][prow][16 + lr] = __float2bfloat16(p1);
          Ps[wid][prow][32 + lr] = __float2bfloat16(p2);
          Ps[wid][prow][48 + lr] = __float2bfloat16(p3);
        }
#pragma unroll
        for (int db = 0; db < 8; ++db) {
          oacc[qr][db][0] *= scl4[0]; oacc[qr][db][1] *= scl4[1];
          oacc[qr][db][2] *= scl4[2]; oacc[qr][db][3] *= scl4[3];
        }
      }
      asm volatile("s_waitcnt lgkmcnt(0)" ::: "memory");
      __builtin_amdgcn_sched_barrier(0);
      bf16x8 pf[2][2];
#pragma unroll
      for (int qr = 0; qr < 2; ++qr)
#pragma unroll
        for (int k2 = 0; k2 < 2; ++k2)
          pf[qr][k2] = *(const bf16x8*)&Ps[wid][qr*16 + lr][k2*32 + lkg*8];
#pragma unroll
      for (int db = 0; db < 8; ++db) {
        bf16x8 vf0 = *(const bf16x8*)&Vs[db*16 + lr][lkg*8];
        bf16x8 vf1 = *(const bf16x8*)&Vs[db*16 + lr][32 + lkg*8];
#pragma unroll
        for (int qr = 0; qr < 2; ++qr) {
          oacc[qr][db] = mfma16(pf[qr][0], vf0, oacc[qr][db]);
          oacc[qr][db] = mfma16(pf[qr][1], vf1, oacc[qr][db]);
        }
      }
    }
  }

  const int b = bh >> 4, h = bh & 15;
#pragma unroll
  for (int qr = 0; qr < 2; ++qr)
#pragma unroll
    for (int reg = 0; reg < 4; ++reg) {
      const float inv = 1.0f / lrow[qr][reg];
      const int row = q0w + qr*16 + lkg*4 + reg;
      bf16* dst = attnA + ((size_t)(b*LL + row)) * MODEL + h * HDIM;
#pragma unroll
      for (int db = 0; db < 8; ++db)
        dst[db*16 + lr] = __float2bfloat16(oacc[qr][db][reg] * inv);
    }
}

// ---------------- launch ----------------
extern "C" void kernel_launch(void* const* d_in, const int* in_sizes, int n_in,
                              void* d_out, int out_size, void* d_ws, size_t ws_size,
                              hipStream_t stream)
{
  const float* x    = (const float*)d_in[0];
  const float* cosT = (const float*)d_in[1];
  const float* sinT = (const float*)d_in[2];
  const float* Wqkv = (const float*)d_in[3];
  const float* Wc   = (const float*)d_in[4];
  const float* bc   = (const float*)d_in[5];
  float* out = (float*)d_out;

  // workspace layout (bytes):
  //   x16    @ 0         : 16,777,216   (reused as attnA later)
  //   WqkvT  @ 16777216  : 25,165,824
  //   WcT    @ 41943040  :  8,388,608
  //   Qb     @ 50331648  : 16,777,216
  //   Kb     @ 67108864  : 16,777,216
  //   VTb    @ 83886080  : 16,777,216   -> total 100,663,296 B
  if (ws_size < 100663296u) return;
  char* w = (char*)d_ws;
  bf16* x16   = (bf16*)(w);
  bf16* WqkvT = (bf16*)(w + (size_t)16777216);
  bf16* WcT   = (bf16*)(w + (size_t)41943040);
  bf16* Qb    = (bf16*)(w + (size_t)50331648);
  bf16* Kb    = (bf16*)(w + (size_t)67108864);
  bf16* VTb   = (bf16*)(w + (size_t)83886080);
  bf16* attnA = x16;   // overlay: x16 dead after GEMM1

  // allow 128KB dynamic LDS (idempotent; not a stream op -> capture-safe)
  hipFuncSetAttribute(reinterpret_cast<const void*>(&k_gemm8<1>),
                      hipFuncAttributeMaxDynamicSharedMemorySize, 131072);
  hipFuncSetAttribute(reinterpret_cast<const void*>(&k_gemm8<2>),
                      hipFuncAttributeMaxDynamicSharedMemorySize, 131072);

  k_cvt<<<(MTOT*MODEL/4 + 255)/256, 256, 0, stream>>>(x, x16, MTOT*MODEL/4);
  k_transpose<<<dim3(N1/32,    MODEL/32), 256, 0, stream>>>(Wqkv, WqkvT, MODEL, N1);
  k_transpose<<<dim3(MODEL/32, MODEL/32), 256, 0, stream>>>(Wc,   WcT,   MODEL, MODEL);

  k_gemm8<1><<<dim3(N1/256, MTOT/256), 512, 131072, stream>>>(
      x16, WqkvT, MTOT, N1, MODEL,
      nullptr, nullptr, Qb, Kb, VTb, cosT, sinT);

  k_attn<<<dim3(LL/128, BB*NHEAD), 256, 0, stream>>>(Qb, Kb, VTb, attnA);

  k_gemm8<2><<<dim3(MODEL/256, MTOT/256), 512, 131072, stream>>>(
      attnA, WcT, MTOT, MODEL, MODEL,
      out, bc, nullptr, nullptr, nullptr, nullptr, nullptr);
}

// Round 5
// 429.140 us; speedup vs baseline: 1.0856x; 1.0856x over previous
//
#include <hip/hip_runtime.h>
#include <hip/hip_bf16.h>

#define MODEL 2048
#define NHEAD 16
#define HDIM  128
#define BB    2
#define LL    2048
#define N1    (3*MODEL)      // 6144
#define MTOT  (BB*LL)        // 4096

typedef __hip_bfloat16 bf16;
typedef __attribute__((ext_vector_type(8))) short bf16x8;
typedef __attribute__((ext_vector_type(4))) float f32x4;

static __device__ __forceinline__ f32x4 mfma16(bf16x8 a, bf16x8 b, f32x4 c) {
  return __builtin_amdgcn_mfma_f32_16x16x32_bf16(a, b, c, 0, 0, 0);
}

// async global->LDS DMA, 16B per lane; LDS base wave-uniform, dest linear
static __device__ __forceinline__ void gl_lds16(const void* g, void* l) {
  __builtin_amdgcn_global_load_lds(
      (const __attribute__((address_space(1))) unsigned int*)g,
      (__attribute__((address_space(3))) unsigned int*)l, 16, 0, 0);
}

// ---------------- prep: f32 -> bf16 (vectorized x4) ----------------
__global__ void k_cvt(const float* __restrict__ in, bf16* __restrict__ out, int n4) {
  int i = blockIdx.x * blockDim.x + threadIdx.x;
  if (i < n4) {
    float4 v = ((const float4*)in)[i];
    bf16* o = out + (size_t)i * 4;
    o[0] = __float2bfloat16(v.x);
    o[1] = __float2bfloat16(v.y);
    o[2] = __float2bfloat16(v.z);
    o[3] = __float2bfloat16(v.w);
  }
}

// ---------------- prep: transpose f32 [R][C] -> bf16 [C][R] ----------------
__global__ __launch_bounds__(256)
void k_transpose(const float* __restrict__ in, bf16* __restrict__ out, int R, int C) {
  __shared__ float t[32][33];
  const int c0 = blockIdx.x * 32, r0 = blockIdx.y * 32;
  const int tx = threadIdx.x & 31;
  const int ty = threadIdx.x >> 5;   // 0..7
#pragma unroll
  for (int i = 0; i < 4; ++i)
    t[ty + 8*i][tx] = in[(size_t)(r0 + ty + 8*i) * C + c0 + tx];
  __syncthreads();
#pragma unroll
  for (int i = 0; i < 4; ++i)
    out[(size_t)(c0 + ty + 8*i) * R + r0 + tx] = __float2bfloat16(t[tx][ty + 8*i]);
}

// ============ 256x256 GEMM, BK=32, 4-buffer deep pipeline ============
// C = A[M][K] * BT[N][K]^T. K-tiles of 32 rotate through 4 LDS buffers:
// A [4buf][2half][128][32] @0 (64KB), B same @65536. Row=64B -> ds_read_b128
// slot = lr*4+lkg: 64 distinct slots mod 32 = 2-way (free), NO swizzle.
// Stage tile t+3 while computing t; vmcnt(8) at tile end completes t+1
// (issued 4-6 phases earlier). 2 phases/tile, 16 MFMA each.
// Grid 1-D with bijective XCD column-chunking (B-panels L2-resident).
// EPI==1: RoPE + scatter Q/K row-major + V^T ; EPI==2: bias + f32 out.

#define BARRIER __builtin_amdgcn_s_barrier()
#define WAIT_LGKM0 { asm volatile("s_waitcnt lgkmcnt(0)" ::: "memory"); __builtin_amdgcn_sched_barrier(0); }
#define WAIT_VM8   { asm volatile("s_waitcnt vmcnt(8)"   ::: "memory"); __builtin_amdgcn_sched_barrier(0); }
#define PRIO1 __builtin_amdgcn_s_setprio(1)
#define PRIO0 __builtin_amdgcn_s_setprio(0)

template<int EPI>
__global__ __launch_bounds__(512, 2)
void k_gemmP(const bf16* __restrict__ A, const bf16* __restrict__ BT,
             int M, int N, int K,
             float* __restrict__ Cout, const float* __restrict__ bias,
             bf16* __restrict__ Qb, bf16* __restrict__ Kb, bf16* __restrict__ VTb,
             const float* __restrict__ cosT, const float* __restrict__ sinT)
{
  extern __shared__ char smem[];      // 131072 B
  const int tid = threadIdx.x;
  const int wid = tid >> 6, lane = tid & 63;
  const int wm = wid >> 2, wn = wid & 3;       // wave grid 2(M) x 4(N)
  const int lr = lane & 15, lkg = lane >> 4;

  // XCD-aware block mapping: column-major chunked (nwg % 8 == 0 here)
  const int nbx = N >> 8, nby = M >> 8;
  const int q = (nbx * nby) >> 3;
  const int lin = (blockIdx.x & 7) * q + (blockIdx.x >> 3);
  const int m0 = (lin % nby) << 8, n0 = (lin / nby) << 8;

  // staging: wave wid owns 32 rows of each 256-row tile; 2 gl_lds per matrix
  const bf16* Asrc = A  + (size_t)(m0 + wid*32 + (lane >> 2)) * K + (lane & 3) * 8;
  const bf16* Bsrc = BT + (size_t)(n0 + wid*32 + (lane >> 2)) * K + (lane & 3) * 8;
  const int dstW = wid * 2048;        // wave's byte region within a 16KB buffer

  // ds_read fragment bases (row = 64B)
  const int aBase = wm*8192 + lr*64 + lkg*16;
  const int bBase = 65536 + (wn >> 1)*8192 + (wn & 1)*4096 + lr*64 + lkg*16;

  const f32x4 vzero = {0.f, 0.f, 0.f, 0.f};
  f32x4 acc[8][4];
#pragma unroll
  for (int i = 0; i < 8; ++i)
#pragma unroll
    for (int j = 0; j < 4; ++j) acc[i][j] = vzero;
  bf16x8 aFr[4], bFr[4];

  const int nt = K >> 5;              // K-tiles of 32 (>= 4)

  // prologue: stage tiles 0,1,2
#pragma unroll
  for (int t = 0; t < 3; ++t) {
    const bf16* as = Asrc + t*32;
    const bf16* bs = Bsrc + t*32;
    const int bo = t * 16384;
    gl_lds16(as,                   smem + bo + dstW);
    gl_lds16(as + (size_t)16*K,    smem + bo + dstW + 1024);
    gl_lds16(bs,                   smem + 65536 + bo + dstW);
    gl_lds16(bs + (size_t)16*K,    smem + 65536 + bo + dstW + 1024);
  }
  WAIT_VM8; BARRIER;                  // tile 0 resident

  for (int t = 0; t < nt; ++t) {
    const int buf  = (t & 3) * 16384;
    const int ts   = (t + 3 < nt) ? t + 3 : nt - 1;   // clamped: data unused
    const int sbuf = ((t + 3) & 3) * 16384;
    const bf16* as = Asrc + ts*32;
    const bf16* bs = Bsrc + ts*32;

    // ---- phase 0: read A-half(wm) frags 0..3 + all B frags; stage A(t+3) ----
#pragma unroll
    for (int mf = 0; mf < 4; ++mf)
      aFr[mf] = *(const bf16x8*)(smem + buf + aBase + mf*1024);
#pragma unroll
    for (int nf = 0; nf < 4; ++nf)
      bFr[nf] = *(const bf16x8*)(smem + buf + bBase + nf*1024);
    gl_lds16(as,                smem + sbuf + dstW);
    gl_lds16(as + (size_t)16*K, smem + sbuf + dstW + 1024);
    BARRIER; WAIT_LGKM0; PRIO1;
#pragma unroll
    for (int mf = 0; mf < 4; ++mf)
#pragma unroll
      for (int nf = 0; nf < 4; ++nf)
        acc[mf][nf] = mfma16(aFr[mf], bFr[nf], acc[mf][nf]);
    PRIO0; BARRIER;

    // ---- phase 1: read A frags 4..7 (B reused); stage B(t+3) ----
#pragma unroll
    for (int mf = 0; mf < 4; ++mf)
      aFr[mf] = *(const bf16x8*)(smem + buf + aBase + (mf + 4)*1024);
    gl_lds16(bs,                smem + 65536 + sbuf + dstW);
    gl_lds16(bs + (size_t)16*K, smem + 65536 + sbuf + dstW + 1024);
    BARRIER; WAIT_LGKM0; PRIO1;
#pragma unroll
    for (int mf = 0; mf < 4; ++mf)
#pragma unroll
      for (int nf = 0; nf < 4; ++nf)
        acc[mf + 4][nf] = mfma16(aFr[mf], bFr[nf], acc[mf + 4][nf]);
    PRIO0; WAIT_VM8; BARRIER;         // tile t+1 now resident
  }

  if constexpr (EPI == 1) {
    const float inv_sqrt_d = 0.08838834764831845f;  // 1/sqrt(128)
#pragma unroll
    for (int nf = 0; nf < 4; ++nf) {
      const int gcb = n0 + wn*64 + nf*16;           // wave-uniform, mult of 16
      const int section = gcb >> 11;                // 0=q 1=k 2=v
      const int cc = (gcb & 2047) + lr;
      const int h = cc >> 7, d = cc & 127;
#pragma unroll
      for (int mf = 0; mf < 8; ++mf) {
#pragma unroll
        for (int reg = 0; reg < 4; ++reg) {
          const int grow = m0 + wm*128 + mf*16 + lkg*4 + reg;
          const int bidx = grow >> 11, lseq = grow & 2047;
          float val = acc[mf][nf][reg];
          if (section < 2) {
            float p = __shfl_xor(val, 1);           // RoPE pair partner
            const int fi = d >> 1;
            float cv = cosT[(size_t)lseq * 64 + fi];
            float sv = sinT[(size_t)lseq * 64 + fi];
            float r = (d & 1) ? fmaf(p, sv, val * cv)
                              : fmaf(val, cv, -p * sv);
            if (section == 0) {
              r *= inv_sqrt_d;
              Qb[((size_t)(bidx*NHEAD + h) * LL + lseq) * HDIM + d] = __float2bfloat16(r);
            } else {
              Kb[((size_t)(bidx*NHEAD + h) * LL + lseq) * HDIM + d] = __float2bfloat16(r);
            }
          } else {
            VTb[((size_t)(bidx*NHEAD + h) * HDIM + d) * LL + lseq] = __float2bfloat16(val);
          }
        }
      }
    }
  } else {
#pragma unroll
    for (int nf = 0; nf < 4; ++nf) {
      const int gcol = n0 + wn*64 + nf*16 + lr;
      const float bv = bias[gcol];
#pragma unroll
      for (int mf = 0; mf < 8; ++mf) {
#pragma unroll
        for (int reg = 0; reg < 4; ++reg) {
          const int grow = m0 + wm*128 + mf*16 + lkg*4 + reg;
          Cout[(size_t)grow * N + gcol] = acc[mf][nf][reg] + bv;
        }
      }
    }
  }
}

// ---------------- flash attention (unchanged) ----------------
__global__ __launch_bounds__(256, 2)
void k_attn(const bf16* __restrict__ Qb, const bf16* __restrict__ Kb,
            const bf16* __restrict__ VTb, bf16* __restrict__ attnA)
{
  __shared__ bf16 Ks[64][136];
  __shared__ bf16 Vs[128][72];
  __shared__ bf16 Ps[4][32][72];

  const int bh  = blockIdx.y;
  const int qb  = (gridDim.x - 1) - blockIdx.x;
  const int tid = threadIdx.x;
  const int wid = tid >> 6, lane = tid & 63;
  const int lr  = lane & 15, lkg = lane >> 4;
  const int Q0  = qb * 128;
  const int q0w = Q0 + wid * 32;

  const bf16* Qh = Qb  + (size_t)bh * LL * HDIM;
  const bf16* Kh = Kb  + (size_t)bh * LL * HDIM;
  const bf16* Vh = VTb + (size_t)bh * HDIM * LL;

  const f32x4 vzero = {0.f, 0.f, 0.f, 0.f};
  bf16x8 qf[2][4];
#pragma unroll
  for (int qr = 0; qr < 2; ++qr)
#pragma unroll
    for (int kk = 0; kk < 4; ++kk)
      qf[qr][kk] = *(const bf16x8*)(Qh + (size_t)(q0w + qr*16 + lr) * HDIM + kk*32 + lkg*8);

  f32x4 oacc[2][8];
#pragma unroll
  for (int qr = 0; qr < 2; ++qr)
#pragma unroll
    for (int db = 0; db < 8; ++db) oacc[qr][db] = vzero;
  float mrow[2][4], lrow[2][4];
#pragma unroll
  for (int qr = 0; qr < 2; ++qr)
#pragma unroll
    for (int r = 0; r < 4; ++r) { mrow[qr][r] = -INFINITY; lrow[qr][r] = 0.f; }

  const int NT = Q0 / 64 + 2;
  bf16x8 kpre[4], vpre[4];
#pragma unroll
  for (int j = 0; j < 4; ++j) {
    const int c = j*256 + tid;
    kpre[j] = *(const bf16x8*)(Kh + (size_t)(c >> 4) * HDIM + (c & 15) * 8);
    vpre[j] = *(const bf16x8*)(Vh + (size_t)(c >> 3) * LL + (c & 7) * 8);
  }

  for (int kt = 0; kt < NT; ++kt) {
    const int kbase = kt * 64;
    __syncthreads();
#pragma unroll
    for (int j = 0; j < 4; ++j) {
      const int c = j*256 + tid;
      *(bf16x8*)&Ks[c >> 4][(c & 15) * 8] = kpre[j];
      *(bf16x8*)&Vs[c >> 3][(c & 7) * 8]  = vpre[j];
    }
    __syncthreads();
    if (kt + 1 < NT) {
#pragma unroll
      for (int j = 0; j < 4; ++j) {
        const int c = j*256 + tid;
        kpre[j] = *(const bf16x8*)(Kh + (size_t)((kt+1)*64 + (c >> 4)) * HDIM + (c & 15) * 8);
        vpre[j] = *(const bf16x8*)(Vh + (size_t)(c >> 3) * LL + (kt+1)*64 + (c & 7) * 8);
      }
    }
    if (kbase <= q0w + 31) {
      f32x4 s[2][4];
#pragma unroll
      for (int qr = 0; qr < 2; ++qr)
#pragma unroll
        for (int c = 0; c < 4; ++c) s[qr][c] = vzero;
#pragma unroll
      for (int c = 0; c < 4; ++c) {
        bf16x8 kf[4];
#pragma unroll
        for (int kk = 0; kk < 4; ++kk)
          kf[kk] = *(const bf16x8*)&Ks[c*16 + lr][kk*32 + lkg*8];
#pragma unroll
        for (int qr = 0; qr < 2; ++qr)
#pragma unroll
          for (int kk = 0; kk < 4; ++kk)
            s[qr][c] = mfma16(qf[qr][kk], kf[kk], s[qr][c]);
      }
#pragma unroll
      for (int qr = 0; qr < 2; ++qr) {
        float scl4[4];
#pragma unroll
        for (int reg = 0; reg < 4; ++reg) {
          const int row = q0w + qr*16 + lkg*4 + reg;
          float v0 = (kbase      + lr <= row) ? s[qr][0][reg] : -INFINITY;
          float v1 = (kbase + 16 + lr <= row) ? s[qr][1][reg] : -INFINITY;
          float v2 = (kbase + 32 + lr <= row) ? s[qr][2][reg] : -INFINITY;
          float v3 = (kbase + 48 + lr <= row) ? s[qr][3][reg] : -INFINITY;
          float tm = fmaxf(fmaxf(v0, v1), fmaxf(v2, v3));
          tm = fmaxf(tm, __shfl_xor(tm, 1));
          tm = fmaxf(tm, __shfl_xor(tm, 2));
          tm = fmaxf(tm, __shfl_xor(tm, 4));
          tm = fmaxf(tm, __shfl_xor(tm, 8));
          const float mnew = fmaxf(mrow[qr][reg], tm);
          const float scl  = __expf(mrow[qr][reg] - mnew);
          mrow[qr][reg] = mnew;
          float p0 = __expf(v0 - mnew);
          float p1 = __expf(v1 - mnew);
          float p2 = __expf(v2 - mnew);
          float p3 = __expf(v3 - mnew);
          float rs = (p0 + p1) + (p2 + p3);
          rs += __shfl_xor(rs, 1);
          rs += __shfl_xor(rs, 2);
          rs += __shfl_xor(rs, 4);
          rs += __shfl_xor(rs, 8);
          lrow[qr][reg] = lrow[qr][reg] * scl + rs;
          scl4[reg] = scl;
          const int prow = qr*16 + lkg*4 + reg;
          Ps[wid][prow][lr]      = __float2bfloat16(p0);
          Ps[wid][prow][16 + lr] = __float2bfloat16(p1);
          Ps[wid][prow][32 + lr] = __float2bfloat16(p2);
          Ps[wid][prow][48 + lr] = __float2bfloat16(p3);
        }
#pragma unroll
        for (int db = 0; db < 8; ++db) {
          oacc[qr][db][0] *= scl4[0]; oacc[qr][db][1] *= scl4[1];
          oacc[qr][db][2] *= scl4[2]; oacc[qr][db][3] *= scl4[3];
        }
      }
      asm volatile("s_waitcnt lgkmcnt(0)" ::: "memory");
      __builtin_amdgcn_sched_barrier(0);
      bf16x8 pf[2][2];
#pragma unroll
      for (int qr = 0; qr < 2; ++qr)
#pragma unroll
        for (int k2 = 0; k2 < 2; ++k2)
          pf[qr][k2] = *(const bf16x8*)&Ps[wid][qr*16 + lr][k2*32 + lkg*8];
#pragma unroll
      for (int db = 0; db < 8; ++db) {
        bf16x8 vf0 = *(const bf16x8*)&Vs[db*16 + lr][lkg*8];
        bf16x8 vf1 = *(const bf16x8*)&Vs[db*16 + lr][32 + lkg*8];
#pragma unroll
        for (int qr = 0; qr < 2; ++qr) {
          oacc[qr][db] = mfma16(pf[qr][0], vf0, oacc[qr][db]);
          oacc[qr][db] = mfma16(pf[qr][1], vf1, oacc[qr][db]);
        }
      }
    }
  }

  const int b = bh >> 4, h = bh & 15;
#pragma unroll
  for (int qr = 0; qr < 2; ++qr)
#pragma unroll
    for (int reg = 0; reg < 4; ++reg) {
      const float inv = 1.0f / lrow[qr][reg];
      const int row = q0w + qr*16 + lkg*4 + reg;
      bf16* dst = attnA + ((size_t)(b*LL + row)) * MODEL + h * HDIM;
#pragma unroll
      for (int db = 0; db < 8; ++db)
        dst[db*16 + lr] = __float2bfloat16(oacc[qr][db][reg] * inv);
    }
}

// ---------------- launch ----------------
extern "C" void kernel_launch(void* const* d_in, const int* in_sizes, int n_in,
                              void* d_out, int out_size, void* d_ws, size_t ws_size,
                              hipStream_t stream)
{
  const float* x    = (const float*)d_in[0];
  const float* cosT = (const float*)d_in[1];
  const float* sinT = (const float*)d_in[2];
  const float* Wqkv = (const float*)d_in[3];
  const float* Wc   = (const float*)d_in[4];
  const float* bc   = (const float*)d_in[5];
  float* out = (float*)d_out;

  // workspace layout (bytes):
  //   x16    @ 0         : 16,777,216   (reused as attnA later)
  //   WqkvT  @ 16777216  : 25,165,824
  //   WcT    @ 41943040  :  8,388,608
  //   Qb     @ 50331648  : 16,777,216
  //   Kb     @ 67108864  : 16,777,216
  //   VTb    @ 83886080  : 16,777,216   -> total 100,663,296 B
  if (ws_size < 100663296u) return;
  char* w = (char*)d_ws;
  bf16* x16   = (bf16*)(w);
  bf16* WqkvT = (bf16*)(w + (size_t)16777216);
  bf16* WcT   = (bf16*)(w + (size_t)41943040);
  bf16* Qb    = (bf16*)(w + (size_t)50331648);
  bf16* Kb    = (bf16*)(w + (size_t)67108864);
  bf16* VTb   = (bf16*)(w + (size_t)83886080);
  bf16* attnA = x16;   // overlay: x16 dead after GEMM1

  // allow 128KB dynamic LDS (idempotent; not a stream op -> capture-safe)
  hipFuncSetAttribute(reinterpret_cast<const void*>(&k_gemmP<1>),
                      hipFuncAttributeMaxDynamicSharedMemorySize, 131072);
  hipFuncSetAttribute(reinterpret_cast<const void*>(&k_gemmP<2>),
                      hipFuncAttributeMaxDynamicSharedMemorySize, 131072);

  k_cvt<<<(MTOT*MODEL/4 + 255)/256, 256, 0, stream>>>(x, x16, MTOT*MODEL/4);
  k_transpose<<<dim3(N1/32,    MODEL/32), 256, 0, stream>>>(Wqkv, WqkvT, MODEL, N1);
  k_transpose<<<dim3(MODEL/32, MODEL/32), 256, 0, stream>>>(Wc,   WcT,   MODEL, MODEL);

  k_gemmP<1><<<(N1/256)*(MTOT/256), 512, 131072, stream>>>(
      x16, WqkvT, MTOT, N1, MODEL,
      nullptr, nullptr, Qb, Kb, VTb, cosT, sinT);

  k_attn<<<dim3(LL/128, BB*NHEAD), 256, 0, stream>>>(Qb, Kb, VTb, attnA);

  k_gemmP<2><<<(MODEL/256)*(MTOT/256), 512, 131072, stream>>>(
      attnA, WcT, MTOT, MODEL, MODEL,
      out, bc, nullptr, nullptr, nullptr, nullptr, nullptr);
}

// Round 6
// 412.732 us; speedup vs baseline: 1.1288x; 1.0398x over previous
//
#include <hip/hip_runtime.h>
#include <hip/hip_bf16.h>

#define MODEL 2048
#define NHEAD 16
#define HDIM  128
#define BB    2
#define LL    2048
#define N1    (3*MODEL)      // 6144
#define MTOT  (BB*LL)        // 4096

typedef __hip_bfloat16 bf16;
typedef __attribute__((ext_vector_type(8))) short bf16x8;
typedef __attribute__((ext_vector_type(4))) float f32x4;

static __device__ __forceinline__ f32x4 mfma16(bf16x8 a, bf16x8 b, f32x4 c) {
  return __builtin_amdgcn_mfma_f32_16x16x32_bf16(a, b, c, 0, 0, 0);
}

// async global->LDS DMA, 16B per lane; LDS base wave-uniform, dest linear
static __device__ __forceinline__ void gl_lds16(const void* g, void* l) {
  __builtin_amdgcn_global_load_lds(
      (const __attribute__((address_space(1))) unsigned int*)g,
      (__attribute__((address_space(3))) unsigned int*)l, 16, 0, 0);
}

// ---------------- prep: f32 -> bf16 (vectorized x4) ----------------
__global__ void k_cvt(const float* __restrict__ in, bf16* __restrict__ out, int n4) {
  int i = blockIdx.x * blockDim.x + threadIdx.x;
  if (i < n4) {
    float4 v = ((const float4*)in)[i];
    bf16* o = out + (size_t)i * 4;
    o[0] = __float2bfloat16(v.x);
    o[1] = __float2bfloat16(v.y);
    o[2] = __float2bfloat16(v.z);
    o[3] = __float2bfloat16(v.w);
  }
}

// ---------------- prep: transpose f32 [R][C] -> bf16 [C][R] ----------------
__global__ __launch_bounds__(256)
void k_transpose(const float* __restrict__ in, bf16* __restrict__ out, int R, int C) {
  __shared__ float t[32][33];
  const int c0 = blockIdx.x * 32, r0 = blockIdx.y * 32;
  const int tx = threadIdx.x & 31;
  const int ty = threadIdx.x >> 5;   // 0..7
#pragma unroll
  for (int i = 0; i < 4; ++i)
    t[ty + 8*i][tx] = in[(size_t)(r0 + ty + 8*i) * C + c0 + tx];
  __syncthreads();
#pragma unroll
  for (int i = 0; i < 4; ++i)
    out[(size_t)(c0 + ty + 8*i) * R + r0 + tx] = __float2bfloat16(t[tx][ty + 8*i]);
}

// ============ 256x256 GEMM, BK=32, 4-buffer deep pipeline ============
// C = A[M][K] * BT[N][K]^T. K-tiles of 32 rotate through 4 LDS buffers:
// A [4buf][2half][128][32] @0 (64KB), B same @65536. Rows are 64 B.
// CONFLICT FIX (r6): 16B-slot swizzle  slot_phys = slot_log ^ ((row>>1)&3).
//   Read:  addr = row*64 + (lkg ^ ((lr>>1)&3))*16  -> lanes 0-15 hit groups
//          {0,4,1,5,2,6,3,7}: all 8 distinct, 2-way max = free.
//   Stage: linear gl_lds dest + inverse-permuted SOURCE slot
//          (l&3) ^ ((l>>3)&3)  (bijective within each row's 4-lane quad).
// Stage tile t+3 while computing t; vmcnt(8) at tile end completes t+1
// (issued ~4-6 phases earlier). 2 phases/tile, 16 MFMA each.
// Grid 1-D with bijective XCD column-chunking.
// EPI==1: RoPE + scatter Q/K row-major + V^T ; EPI==2: bias + f32 out.

#define BARRIER __builtin_amdgcn_s_barrier()
#define WAIT_LGKM0 { asm volatile("s_waitcnt lgkmcnt(0)" ::: "memory"); __builtin_amdgcn_sched_barrier(0); }
#define WAIT_VM8   { asm volatile("s_waitcnt vmcnt(8)"   ::: "memory"); __builtin_amdgcn_sched_barrier(0); }
#define PRIO1 __builtin_amdgcn_s_setprio(1)
#define PRIO0 __builtin_amdgcn_s_setprio(0)

template<int EPI>
__global__ __launch_bounds__(512, 2)
void k_gemmP(const bf16* __restrict__ A, const bf16* __restrict__ BT,
             int M, int N, int K,
             float* __restrict__ Cout, const float* __restrict__ bias,
             bf16* __restrict__ Qb, bf16* __restrict__ Kb, bf16* __restrict__ VTb,
             const float* __restrict__ cosT, const float* __restrict__ sinT)
{
  extern __shared__ char smem[];      // 131072 B
  const int tid = threadIdx.x;
  const int wid = tid >> 6, lane = tid & 63;
  const int wm = wid >> 2, wn = wid & 3;       // wave grid 2(M) x 4(N)
  const int lr = lane & 15, lkg = lane >> 4;

  // XCD-aware block mapping: column-major chunked (nwg % 8 == 0 here)
  const int nbx = N >> 8, nby = M >> 8;
  const int qq = (nbx * nby) >> 3;
  const int lin = (blockIdx.x & 7) * qq + (blockIdx.x >> 3);
  const int m0 = (lin % nby) << 8, n0 = (lin / nby) << 8;

  // staging: wave wid owns 32 rows of each 256-row tile; source slot carries
  // the inverse swizzle so linear LDS dest ends up slot-permuted per row
  const int scol = ((lane & 3) ^ ((lane >> 3) & 3)) * 8;   // bf16 elems
  const bf16* Asrc = A  + (size_t)(m0 + wid*32 + (lane >> 2)) * K + scol;
  const bf16* Bsrc = BT + (size_t)(n0 + wid*32 + (lane >> 2)) * K + scol;
  const int dstW = wid * 2048;        // wave's byte region within a 16KB buffer

  // ds_read fragment bases (row = 64B, slot XOR-swizzled by row bits 1-2)
  const int slotX = (lkg ^ ((lr >> 1) & 3)) * 16;
  const int aBase = wm*8192 + lr*64 + slotX;
  const int bBase = 65536 + (wn >> 1)*8192 + (wn & 1)*4096 + lr*64 + slotX;

  const f32x4 vzero = {0.f, 0.f, 0.f, 0.f};
  f32x4 acc[8][4];
#pragma unroll
  for (int i = 0; i < 8; ++i)
#pragma unroll
    for (int j = 0; j < 4; ++j) acc[i][j] = vzero;
  bf16x8 aFr[4], bFr[4];

  const int nt = K >> 5;              // K-tiles of 32 (>= 4)

  // prologue: stage tiles 0,1,2
#pragma unroll
  for (int t = 0; t < 3; ++t) {
    const bf16* as = Asrc + t*32;
    const bf16* bs = Bsrc + t*32;
    const int bo = t * 16384;
    gl_lds16(as,                   smem + bo + dstW);
    gl_lds16(as + (size_t)16*K,    smem + bo + dstW + 1024);
    gl_lds16(bs,                   smem + 65536 + bo + dstW);
    gl_lds16(bs + (size_t)16*K,    smem + 65536 + bo + dstW + 1024);
  }
  WAIT_VM8; BARRIER;                  // tile 0 resident

  for (int t = 0; t < nt; ++t) {
    const int buf  = (t & 3) * 16384;
    const int ts   = (t + 3 < nt) ? t + 3 : nt - 1;   // clamped: data unused
    const int sbuf = ((t + 3) & 3) * 16384;
    const bf16* as = Asrc + ts*32;
    const bf16* bs = Bsrc + ts*32;

    // ---- phase 0: read A-half(wm) frags 0..3 + all B frags; stage A(t+3) ----
#pragma unroll
    for (int mf = 0; mf < 4; ++mf)
      aFr[mf] = *(const bf16x8*)(smem + buf + aBase + mf*1024);
#pragma unroll
    for (int nf = 0; nf < 4; ++nf)
      bFr[nf] = *(const bf16x8*)(smem + buf + bBase + nf*1024);
    gl_lds16(as,                smem + sbuf + dstW);
    gl_lds16(as + (size_t)16*K, smem + sbuf + dstW + 1024);
    BARRIER; WAIT_LGKM0; PRIO1;
#pragma unroll
    for (int mf = 0; mf < 4; ++mf)
#pragma unroll
      for (int nf = 0; nf < 4; ++nf)
        acc[mf][nf] = mfma16(aFr[mf], bFr[nf], acc[mf][nf]);
    PRIO0; BARRIER;

    // ---- phase 1: read A frags 4..7 (B reused); stage B(t+3) ----
#pragma unroll
    for (int mf = 0; mf < 4; ++mf)
      aFr[mf] = *(const bf16x8*)(smem + buf + aBase + (mf + 4)*1024);
    gl_lds16(bs,                smem + 65536 + sbuf + dstW);
    gl_lds16(bs + (size_t)16*K, smem + 65536 + sbuf + dstW + 1024);
    BARRIER; WAIT_LGKM0; PRIO1;
#pragma unroll
    for (int mf = 0; mf < 4; ++mf)
#pragma unroll
      for (int nf = 0; nf < 4; ++nf)
        acc[mf + 4][nf] = mfma16(aFr[mf], bFr[nf], acc[mf + 4][nf]);
    PRIO0; WAIT_VM8; BARRIER;         // tile t+1 now resident
  }

  if constexpr (EPI == 1) {
    const float inv_sqrt_d = 0.08838834764831845f;  // 1/sqrt(128)
#pragma unroll
    for (int nf = 0; nf < 4; ++nf) {
      const int gcb = n0 + wn*64 + nf*16;           // wave-uniform, mult of 16
      const int section = gcb >> 11;                // 0=q 1=k 2=v
      const int cc = (gcb & 2047) + lr;
      const int h = cc >> 7, d = cc & 127;
#pragma unroll
      for (int mf = 0; mf < 8; ++mf) {
#pragma unroll
        for (int reg = 0; reg < 4; ++reg) {
          const int grow = m0 + wm*128 + mf*16 + lkg*4 + reg;
          const int bidx = grow >> 11, lseq = grow & 2047;
          float val = acc[mf][nf][reg];
          if (section < 2) {
            float p = __shfl_xor(val, 1);           // RoPE pair partner
            const int fi = d >> 1;
            float cv = cosT[(size_t)lseq * 64 + fi];
            float sv = sinT[(size_t)lseq * 64 + fi];
            float r = (d & 1) ? fmaf(p, sv, val * cv)
                              : fmaf(val, cv, -p * sv);
            if (section == 0) {
              r *= inv_sqrt_d;
              Qb[((size_t)(bidx*NHEAD + h) * LL + lseq) * HDIM + d] = __float2bfloat16(r);
            } else {
              Kb[((size_t)(bidx*NHEAD + h) * LL + lseq) * HDIM + d] = __float2bfloat16(r);
            }
          } else {
            VTb[((size_t)(bidx*NHEAD + h) * HDIM + d) * LL + lseq] = __float2bfloat16(val);
          }
        }
      }
    }
  } else {
#pragma unroll
    for (int nf = 0; nf < 4; ++nf) {
      const int gcol = n0 + wn*64 + nf*16 + lr;
      const float bv = bias[gcol];
#pragma unroll
      for (int mf = 0; mf < 8; ++mf) {
#pragma unroll
        for (int reg = 0; reg < 4; ++reg) {
          const int grow = m0 + wm*128 + mf*16 + lkg*4 + reg;
          Cout[(size_t)grow * N + gcol] = acc[mf][nf][reg] + bv;
        }
      }
    }
  }
}

// ---------------- flash attention (unchanged) ----------------
__global__ __launch_bounds__(256, 2)
void k_attn(const bf16* __restrict__ Qb, const bf16* __restrict__ Kb,
            const bf16* __restrict__ VTb, bf16* __restrict__ attnA)
{
  __shared__ bf16 Ks[64][136];
  __shared__ bf16 Vs[128][72];
  __shared__ bf16 Ps[4][32][72];

  const int bh  = blockIdx.y;
  const int qb  = (gridDim.x - 1) - blockIdx.x;
  const int tid = threadIdx.x;
  const int wid = tid >> 6, lane = tid & 63;
  const int lr  = lane & 15, lkg = lane >> 4;
  const int Q0  = qb * 128;
  const int q0w = Q0 + wid * 32;

  const bf16* Qh = Qb  + (size_t)bh * LL * HDIM;
  const bf16* Kh = Kb  + (size_t)bh * LL * HDIM;
  const bf16* Vh = VTb + (size_t)bh * HDIM * LL;

  const f32x4 vzero = {0.f, 0.f, 0.f, 0.f};
  bf16x8 qf[2][4];
#pragma unroll
  for (int qr = 0; qr < 2; ++qr)
#pragma unroll
    for (int kk = 0; kk < 4; ++kk)
      qf[qr][kk] = *(const bf16x8*)(Qh + (size_t)(q0w + qr*16 + lr) * HDIM + kk*32 + lkg*8);

  f32x4 oacc[2][8];
#pragma unroll
  for (int qr = 0; qr < 2; ++qr)
#pragma unroll
    for (int db = 0; db < 8; ++db) oacc[qr][db] = vzero;
  float mrow[2][4], lrow[2][4];
#pragma unroll
  for (int qr = 0; qr < 2; ++qr)
#pragma unroll
    for (int r = 0; r < 4; ++r) { mrow[qr][r] = -INFINITY; lrow[qr][r] = 0.f; }

  const int NT = Q0 / 64 + 2;
  bf16x8 kpre[4], vpre[4];
#pragma unroll
  for (int j = 0; j < 4; ++j) {
    const int c = j*256 + tid;
    kpre[j] = *(const bf16x8*)(Kh + (size_t)(c >> 4) * HDIM + (c & 15) * 8);
    vpre[j] = *(const bf16x8*)(Vh + (size_t)(c >> 3) * LL + (c & 7) * 8);
  }

  for (int kt = 0; kt < NT; ++kt) {
    const int kbase = kt * 64;
    __syncthreads();
#pragma unroll
    for (int j = 0; j < 4; ++j) {
      const int c = j*256 + tid;
      *(bf16x8*)&Ks[c >> 4][(c & 15) * 8] = kpre[j];
      *(bf16x8*)&Vs[c >> 3][(c & 7) * 8]  = vpre[j];
    }
    __syncthreads();
    if (kt + 1 < NT) {
#pragma unroll
      for (int j = 0; j < 4; ++j) {
        const int c = j*256 + tid;
        kpre[j] = *(const bf16x8*)(Kh + (size_t)((kt+1)*64 + (c >> 4)) * HDIM + (c & 15) * 8);
        vpre[j] = *(const bf16x8*)(Vh + (size_t)(c >> 3) * LL + (kt+1)*64 + (c & 7) * 8);
      }
    }
    if (kbase <= q0w + 31) {
      f32x4 s[2][4];
#pragma unroll
      for (int qr = 0; qr < 2; ++qr)
#pragma unroll
        for (int c = 0; c < 4; ++c) s[qr][c] = vzero;
#pragma unroll
      for (int c = 0; c < 4; ++c) {
        bf16x8 kf[4];
#pragma unroll
        for (int kk = 0; kk < 4; ++kk)
          kf[kk] = *(const bf16x8*)&Ks[c*16 + lr][kk*32 + lkg*8];
#pragma unroll
        for (int qr = 0; qr < 2; ++qr)
#pragma unroll
          for (int kk = 0; kk < 4; ++kk)
            s[qr][c] = mfma16(qf[qr][kk], kf[kk], s[qr][c]);
      }
#pragma unroll
      for (int qr = 0; qr < 2; ++qr) {
        float scl4[4];
#pragma unroll
        for (int reg = 0; reg < 4; ++reg) {
          const int row = q0w + qr*16 + lkg*4 + reg;
          float v0 = (kbase      + lr <= row) ? s[qr][0][reg] : -INFINITY;
          float v1 = (kbase + 16 + lr <= row) ? s[qr][1][reg] : -INFINITY;
          float v2 = (kbase + 32 + lr <= row) ? s[qr][2][reg] : -INFINITY;
          float v3 = (kbase + 48 + lr <= row) ? s[qr][3][reg] : -INFINITY;
          float tm = fmaxf(fmaxf(v0, v1), fmaxf(v2, v3));
          tm = fmaxf(tm, __shfl_xor(tm, 1));
          tm = fmaxf(tm, __shfl_xor(tm, 2));
          tm = fmaxf(tm, __shfl_xor(tm, 4));
          tm = fmaxf(tm, __shfl_xor(tm, 8));
          const float mnew = fmaxf(mrow[qr][reg], tm);
          const float scl  = __expf(mrow[qr][reg] - mnew);
          mrow[qr][reg] = mnew;
          float p0 = __expf(v0 - mnew);
          float p1 = __expf(v1 - mnew);
          float p2 = __expf(v2 - mnew);
          float p3 = __expf(v3 - mnew);
          float rs = (p0 + p1) + (p2 + p3);
          rs += __shfl_xor(rs, 1);
          rs += __shfl_xor(rs, 2);
          rs += __shfl_xor(rs, 4);
          rs += __shfl_xor(rs, 8);
          lrow[qr][reg] = lrow[qr][reg] * scl + rs;
          scl4[reg] = scl;
          const int prow = qr*16 + lkg*4 + reg;
          Ps[wid][prow][lr]      = __float2bfloat16(p0);
          Ps[wid][prow][16 + lr] = __float2bfloat16(p1);
          Ps[wid][prow][32 + lr] = __float2bfloat16(p2);
          Ps[wid][prow][48 + lr] = __float2bfloat16(p3);
        }
#pragma unroll
        for (int db = 0; db < 8; ++db) {
          oacc[qr][db][0] *= scl4[0]; oacc[qr][db][1] *= scl4[1];
          oacc[qr][db][2] *= scl4[2]; oacc[qr][db][3] *= scl4[3];
        }
      }
      asm volatile("s_waitcnt lgkmcnt(0)" ::: "memory");
      __builtin_amdgcn_sched_barrier(0);
      bf16x8 pf[2][2];
#pragma unroll
      for (int qr = 0; qr < 2; ++qr)
#pragma unroll
        for (int k2 = 0; k2 < 2; ++k2)
          pf[qr][k2] = *(const bf16x8*)&Ps[wid][qr*16 + lr][k2*32 + lkg*8];
#pragma unroll
      for (int db = 0; db < 8; ++db) {
        bf16x8 vf0 = *(const bf16x8*)&Vs[db*16 + lr][lkg*8];
        bf16x8 vf1 = *(const bf16x8*)&Vs[db*16 + lr][32 + lkg*8];
#pragma unroll
        for (int qr = 0; qr < 2; ++qr) {
          oacc[qr][db] = mfma16(pf[qr][0], vf0, oacc[qr][db]);
          oacc[qr][db] = mfma16(pf[qr][1], vf1, oacc[qr][db]);
        }
      }
    }
  }

  const int b = bh >> 4, h = bh & 15;
#pragma unroll
  for (int qr = 0; qr < 2; ++qr)
#pragma unroll
    for (int reg = 0; reg < 4; ++reg) {
      const float inv = 1.0f / lrow[qr][reg];
      const int row = q0w + qr*16 + lkg*4 + reg;
      bf16* dst = attnA + ((size_t)(b*LL + row)) * MODEL + h * HDIM;
#pragma unroll
      for (int db = 0; db < 8; ++db)
        dst[db*16 + lr] = __float2bfloat16(oacc[qr][db][reg] * inv);
    }
}

// ---------------- launch ----------------
extern "C" void kernel_launch(void* const* d_in, const int* in_sizes, int n_in,
                              void* d_out, int out_size, void* d_ws, size_t ws_size,
                              hipStream_t stream)
{
  const float* x    = (const float*)d_in[0];
  const float* cosT = (const float*)d_in[1];
  const float* sinT = (const float*)d_in[2];
  const float* Wqkv = (const float*)d_in[3];
  const float* Wc   = (const float*)d_in[4];
  const float* bc   = (const float*)d_in[5];
  float* out = (float*)d_out;

  // workspace layout (bytes):
  //   x16    @ 0         : 16,777,216   (reused as attnA later)
  //   WqkvT  @ 16777216  : 25,165,824
  //   WcT    @ 41943040  :  8,388,608
  //   Qb     @ 50331648  : 16,777,216
  //   Kb     @ 67108864  : 16,777,216
  //   VTb    @ 83886080  : 16,777,216   -> total 100,663,296 B
  if (ws_size < 100663296u) return;
  char* w = (char*)d_ws;
  bf16* x16   = (bf16*)(w);
  bf16* WqkvT = (bf16*)(w + (size_t)16777216);
  bf16* WcT   = (bf16*)(w + (size_t)41943040);
  bf16* Qb    = (bf16*)(w + (size_t)50331648);
  bf16* Kb    = (bf16*)(w + (size_t)67108864);
  bf16* VTb   = (bf16*)(w + (size_t)83886080);
  bf16* attnA = x16;   // overlay: x16 dead after GEMM1

  // allow 128KB dynamic LDS (idempotent; not a stream op -> capture-safe)
  hipFuncSetAttribute(reinterpret_cast<const void*>(&k_gemmP<1>),
                      hipFuncAttributeMaxDynamicSharedMemorySize, 131072);
  hipFuncSetAttribute(reinterpret_cast<const void*>(&k_gemmP<2>),
                      hipFuncAttributeMaxDynamicSharedMemorySize, 131072);

  k_cvt<<<(MTOT*MODEL/4 + 255)/256, 256, 0, stream>>>(x, x16, MTOT*MODEL/4);
  k_transpose<<<dim3(N1/32,    MODEL/32), 256, 0, stream>>>(Wqkv, WqkvT, MODEL, N1);
  k_transpose<<<dim3(MODEL/32, MODEL/32), 256, 0, stream>>>(Wc,   WcT,   MODEL, MODEL);

  k_gemmP<1><<<(N1/256)*(MTOT/256), 512, 131072, stream>>>(
      x16, WqkvT, MTOT, N1, MODEL,
      nullptr, nullptr, Qb, Kb, VTb, cosT, sinT);

  k_attn<<<dim3(LL/128, BB*NHEAD), 256, 0, stream>>>(Qb, Kb, VTb, attnA);

  k_gemmP<2><<<(MODEL/256)*(MTOT/256), 512, 131072, stream>>>(
      attnA, WcT, MTOT, MODEL, MODEL,
      out, bc, nullptr, nullptr, nullptr, nullptr, nullptr);
}

// Round 7
// 388.299 us; speedup vs baseline: 1.1998x; 1.0629x over previous
//
#include <hip/hip_runtime.h>
#include <hip/hip_bf16.h>

#define MODEL 2048
#define NHEAD 16
#define HDIM  128
#define BB    2
#define LL    2048
#define N1    (3*MODEL)      // 6144
#define MTOT  (BB*LL)        // 4096

typedef __hip_bfloat16 bf16;
typedef __attribute__((ext_vector_type(8))) short bf16x8;
typedef __attribute__((ext_vector_type(4))) float f32x4;

static __device__ __forceinline__ f32x4 mfma16(bf16x8 a, bf16x8 b, f32x4 c) {
  return __builtin_amdgcn_mfma_f32_16x16x32_bf16(a, b, c, 0, 0, 0);
}

// async global->LDS DMA, 16B per lane; LDS base wave-uniform, dest linear
static __device__ __forceinline__ void gl_lds16(const void* g, void* l) {
  __builtin_amdgcn_global_load_lds(
      (const __attribute__((address_space(1))) unsigned int*)g,
      (__attribute__((address_space(3))) unsigned int*)l, 16, 0, 0);
}

// ---------------- prep: f32 -> bf16 (vectorized x4) ----------------
__global__ void k_cvt(const float* __restrict__ in, bf16* __restrict__ out, int n4) {
  int i = blockIdx.x * blockDim.x + threadIdx.x;
  if (i < n4) {
    float4 v = ((const float4*)in)[i];
    bf16* o = out + (size_t)i * 4;
    o[0] = __float2bfloat16(v.x);
    o[1] = __float2bfloat16(v.y);
    o[2] = __float2bfloat16(v.z);
    o[3] = __float2bfloat16(v.w);
  }
}

// ---------------- prep: transpose f32 [R][C] -> bf16 [C][R] ----------------
__global__ __launch_bounds__(256)
void k_transpose(const float* __restrict__ in, bf16* __restrict__ out, int R, int C) {
  __shared__ float t[32][33];
  const int c0 = blockIdx.x * 32, r0 = blockIdx.y * 32;
  const int tx = threadIdx.x & 31;
  const int ty = threadIdx.x >> 5;   // 0..7
#pragma unroll
  for (int i = 0; i < 4; ++i)
    t[ty + 8*i][tx] = in[(size_t)(r0 + ty + 8*i) * C + c0 + tx];
  __syncthreads();
#pragma unroll
  for (int i = 0; i < 4; ++i)
    out[(size_t)(c0 + ty + 8*i) * R + r0 + tx] = __float2bfloat16(t[tx][ty + 8*i]);
}

// ============ BMx256 GEMM, BK=32, 4-buffer pipeline, 1 barrier/tile ============
// C = A[M][K] * BT[N][K]^T. K-tiles of 32 rotate through 4 LDS buffers.
// A [4buf][BM][32] @0, B [4buf][256][32] @AREG. Rows are 64 B.
// Slot swizzle (r6, verified conflict-free): read 16B-slot = lkg ^ ((lr>>1)&3);
// staged via inverse-permuted SOURCE slot (l&3)^((l>>3)&3), linear LDS dest.
// r7: ONE barrier + ONE vm-wait per tile (mid-tile barriers removed) so the
// LDS pipe and matrix pipe overlap across drifting waves. Counted lgkm(4)
// starts the first MFMA half while A4-7 drain (BM=256).
// Correctness: tile-end barrier (after per-wave vmcnt<=2*VMT) guarantees
// (a) all waves' loads for tile t+1 landed, (b) all waves finished tile t's
// ds_reads (their lgkm0 precedes MFMA precedes barrier) -> restage of buffer
// (t-1)&3 during tile t+1 is safe.
// EPI==1 (BM=256): RoPE + scatter Q/K row-major + V^T ; EPI==2: bias + f32.

#define BARRIER __builtin_amdgcn_s_barrier()
#define SCHED0  __builtin_amdgcn_sched_barrier(0)
#define PRIO1 __builtin_amdgcn_s_setprio(1)
#define PRIO0 __builtin_amdgcn_s_setprio(0)

template<int EPI, int BM>
__global__ __launch_bounds__(512, 2)
void k_gemmP(const bf16* __restrict__ A, const bf16* __restrict__ BT,
             int M, int N, int K,
             float* __restrict__ Cout, const float* __restrict__ bias,
             bf16* __restrict__ Qb, bf16* __restrict__ Kb, bf16* __restrict__ VTb,
             const float* __restrict__ cosT, const float* __restrict__ sinT)
{
  constexpr int MF   = BM / 32;        // A frags per wave (8 or 4)
  constexpr int ABUF = BM * 64;        // A tile bytes (16K / 8K)
  constexpr int AREG = 4 * ABUF;       // A region bytes
  constexpr int BBUF = 16384;          // B tile bytes
  extern __shared__ char smem[];

  const int tid = threadIdx.x;
  const int wid = tid >> 6, lane = tid & 63;
  const int wm = wid >> 2, wn = wid & 3;       // wave grid 2(M) x 4(N)
  const int lr = lane & 15, lkg = lane >> 4;

  // XCD-aware block mapping: column-major chunked (nwg % 8 == 0)
  const int nby = M / BM;
  const int qq = ((N >> 8) * nby) >> 3;
  const int lin = (blockIdx.x & 7) * qq + (blockIdx.x >> 3);
  const int m0 = (lin % nby) * BM, n0 = (lin / nby) << 8;

  // staging: source slot carries inverse swizzle; LDS dest linear
  const int scol = ((lane & 3) ^ ((lane >> 3) & 3)) * 8;   // bf16 elems
  const bf16* Asrc = A  + (size_t)(m0 + wid*(BM/8) + (lane >> 2)) * K + scol;
  const bf16* Bsrc = BT + (size_t)(n0 + wid*32     + (lane >> 2)) * K + scol;

  auto stageA = [&](int t) {
    const bf16* g = Asrc + t*32;
    char* d = smem + (t & 3)*ABUF + wid*(BM*8);
    gl_lds16(g, d);
    if constexpr (BM == 256) gl_lds16(g + (size_t)16*K, d + 1024);
  };
  auto stageB = [&](int t) {
    const bf16* g = Bsrc + t*32;
    char* d = smem + AREG + (t & 3)*BBUF + wid*2048;
    gl_lds16(g, d);
    gl_lds16(g + (size_t)16*K, d + 1024);
  };

  // ds_read fragment bases (row = 64B, slot XOR-swizzled by row bits 1-2)
  const int slotX = (lkg ^ ((lr >> 1) & 3)) * 16;
  const int aBase = wm*(BM*32) + lr*64 + slotX;
  const int bBase = AREG + (wn >> 1)*8192 + (wn & 1)*4096 + lr*64 + slotX;

  const f32x4 vzero = {0.f, 0.f, 0.f, 0.f};
  f32x4 acc[MF][4];
#pragma unroll
  for (int i = 0; i < MF; ++i)
#pragma unroll
    for (int j = 0; j < 4; ++j) acc[i][j] = vzero;

  const int nt = K >> 5;              // K-tiles of 32 (>= 4)

  // prologue: stage tiles 0,1,2 -> wait until tile 0's loads complete
  stageA(0); stageB(0); stageA(1); stageB(1); stageA(2); stageB(2);
  if constexpr (BM == 256) { asm volatile("s_waitcnt vmcnt(8)" ::: "memory"); }
  else                     { asm volatile("s_waitcnt vmcnt(6)" ::: "memory"); }
  SCHED0; BARRIER;

  for (int t = 0; t < nt; ++t) {
    const int bufA = (t & 3) * ABUF;
    const int bufB = (t & 3) * BBUF;
    const int ts   = (t + 3 < nt) ? t + 3 : nt - 1;   // clamp: data unused
    bf16x8 aFr[MF], bFr[4];

    // issue all ds_reads (A0-3, B0-3 first; then A4-7 if BM=256)
#pragma unroll
    for (int mf = 0; mf < 4 && mf < MF; ++mf)
      aFr[mf] = *(const bf16x8*)(smem + bufA + aBase + mf*1024);
#pragma unroll
    for (int nf = 0; nf < 4; ++nf)
      bFr[nf] = *(const bf16x8*)(smem + bufB + bBase + nf*1024);
    if constexpr (MF == 8) {
#pragma unroll
      for (int mf = 4; mf < 8; ++mf)
        aFr[mf] = *(const bf16x8*)(smem + bufA + aBase + mf*1024);
    }
    // issue next-tile staging (overlaps with everything below)
    stageA(ts); stageB(ts);

    if constexpr (MF == 8) { asm volatile("s_waitcnt lgkmcnt(4)" ::: "memory"); }
    else                   { asm volatile("s_waitcnt lgkmcnt(0)" ::: "memory"); }
    SCHED0;
    PRIO1;
#pragma unroll
    for (int mf = 0; mf < 4 && mf < MF; ++mf)
#pragma unroll
      for (int nf = 0; nf < 4; ++nf)
        acc[mf][nf] = mfma16(aFr[mf], bFr[nf], acc[mf][nf]);
    if constexpr (MF == 8) {
      asm volatile("s_waitcnt lgkmcnt(0)" ::: "memory"); SCHED0;
#pragma unroll
      for (int mf = 4; mf < 8; ++mf)
#pragma unroll
        for (int nf = 0; nf < 4; ++nf)
          acc[mf][nf] = mfma16(aFr[mf], bFr[nf], acc[mf][nf]);
    }
    PRIO0;
    // complete tile t+1's loads (issued at t-2): outstanding <= 2 tiles' worth
    if constexpr (BM == 256) { asm volatile("s_waitcnt vmcnt(8)" ::: "memory"); }
    else                     { asm volatile("s_waitcnt vmcnt(6)" ::: "memory"); }
    SCHED0;
    BARRIER;                          // single collective sync per tile
  }

  if constexpr (EPI == 1) {
    const float inv_sqrt_d = 0.08838834764831845f;  // 1/sqrt(128)
#pragma unroll
    for (int nf = 0; nf < 4; ++nf) {
      const int gcb = n0 + wn*64 + nf*16;           // wave-uniform, mult of 16
      const int section = gcb >> 11;                // 0=q 1=k 2=v
      const int cc = (gcb & 2047) + lr;
      const int h = cc >> 7, d = cc & 127;
#pragma unroll
      for (int mf = 0; mf < MF; ++mf) {
#pragma unroll
        for (int reg = 0; reg < 4; ++reg) {
          const int grow = m0 + wm*(BM/2) + mf*16 + lkg*4 + reg;
          const int bidx = grow >> 11, lseq = grow & 2047;
          float val = acc[mf][nf][reg];
          if (section < 2) {
            float p = __shfl_xor(val, 1);           // RoPE pair partner
            const int fi = d >> 1;
            float cv = cosT[(size_t)lseq * 64 + fi];
            float sv = sinT[(size_t)lseq * 64 + fi];
            float r = (d & 1) ? fmaf(p, sv, val * cv)
                              : fmaf(val, cv, -p * sv);
            if (section == 0) {
              r *= inv_sqrt_d;
              Qb[((size_t)(bidx*NHEAD + h) * LL + lseq) * HDIM + d] = __float2bfloat16(r);
            } else {
              Kb[((size_t)(bidx*NHEAD + h) * LL + lseq) * HDIM + d] = __float2bfloat16(r);
            }
          } else {
            VTb[((size_t)(bidx*NHEAD + h) * HDIM + d) * LL + lseq] = __float2bfloat16(val);
          }
        }
      }
    }
  } else {
#pragma unroll
    for (int nf = 0; nf < 4; ++nf) {
      const int gcol = n0 + wn*64 + nf*16 + lr;
      const float bv = bias[gcol];
#pragma unroll
      for (int mf = 0; mf < MF; ++mf) {
#pragma unroll
        for (int reg = 0; reg < 4; ++reg) {
          const int grow = m0 + wm*(BM/2) + mf*16 + lkg*4 + reg;
          Cout[(size_t)grow * N + gcol] = acc[mf][nf][reg] + bv;
        }
      }
    }
  }
}

// ---------------- flash attention (unchanged) ----------------
__global__ __launch_bounds__(256, 2)
void k_attn(const bf16* __restrict__ Qb, const bf16* __restrict__ Kb,
            const bf16* __restrict__ VTb, bf16* __restrict__ attnA)
{
  __shared__ bf16 Ks[64][136];
  __shared__ bf16 Vs[128][72];
  __shared__ bf16 Ps[4][32][72];

  const int bh  = blockIdx.y;
  const int qb  = (gridDim.x - 1) - blockIdx.x;
  const int tid = threadIdx.x;
  const int wid = tid >> 6, lane = tid & 63;
  const int lr  = lane & 15, lkg = lane >> 4;
  const int Q0  = qb * 128;
  const int q0w = Q0 + wid * 32;

  const bf16* Qh = Qb  + (size_t)bh * LL * HDIM;
  const bf16* Kh = Kb  + (size_t)bh * LL * HDIM;
  const bf16* Vh = VTb + (size_t)bh * HDIM * LL;

  const f32x4 vzero = {0.f, 0.f, 0.f, 0.f};
  bf16x8 qf[2][4];
#pragma unroll
  for (int qr = 0; qr < 2; ++qr)
#pragma unroll
    for (int kk = 0; kk < 4; ++kk)
      qf[qr][kk] = *(const bf16x8*)(Qh + (size_t)(q0w + qr*16 + lr) * HDIM + kk*32 + lkg*8);

  f32x4 oacc[2][8];
#pragma unroll
  for (int qr = 0; qr < 2; ++qr)
#pragma unroll
    for (int db = 0; db < 8; ++db) oacc[qr][db] = vzero;
  float mrow[2][4], lrow[2][4];
#pragma unroll
  for (int qr = 0; qr < 2; ++qr)
#pragma unroll
    for (int r = 0; r < 4; ++r) { mrow[qr][r] = -INFINITY; lrow[qr][r] = 0.f; }

  const int NT = Q0 / 64 + 2;
  bf16x8 kpre[4], vpre[4];
#pragma unroll
  for (int j = 0; j < 4; ++j) {
    const int c = j*256 + tid;
    kpre[j] = *(const bf16x8*)(Kh + (size_t)(c >> 4) * HDIM + (c & 15) * 8);
    vpre[j] = *(const bf16x8*)(Vh + (size_t)(c >> 3) * LL + (c & 7) * 8);
  }

  for (int kt = 0; kt < NT; ++kt) {
    const int kbase = kt * 64;
    __syncthreads();
#pragma unroll
    for (int j = 0; j < 4; ++j) {
      const int c = j*256 + tid;
      *(bf16x8*)&Ks[c >> 4][(c & 15) * 8] = kpre[j];
      *(bf16x8*)&Vs[c >> 3][(c & 7) * 8]  = vpre[j];
    }
    __syncthreads();
    if (kt + 1 < NT) {
#pragma unroll
      for (int j = 0; j < 4; ++j) {
        const int c = j*256 + tid;
        kpre[j] = *(const bf16x8*)(Kh + (size_t)((kt+1)*64 + (c >> 4)) * HDIM + (c & 15) * 8);
        vpre[j] = *(const bf16x8*)(Vh + (size_t)(c >> 3) * LL + (kt+1)*64 + (c & 7) * 8);
      }
    }
    if (kbase <= q0w + 31) {
      f32x4 s[2][4];
#pragma unroll
      for (int qr = 0; qr < 2; ++qr)
#pragma unroll
        for (int c = 0; c < 4; ++c) s[qr][c] = vzero;
#pragma unroll
      for (int c = 0; c < 4; ++c) {
        bf16x8 kf[4];
#pragma unroll
        for (int kk = 0; kk < 4; ++kk)
          kf[kk] = *(const bf16x8*)&Ks[c*16 + lr][kk*32 + lkg*8];
#pragma unroll
        for (int qr = 0; qr < 2; ++qr)
#pragma unroll
          for (int kk = 0; kk < 4; ++kk)
            s[qr][c] = mfma16(qf[qr][kk], kf[kk], s[qr][c]);
      }
#pragma unroll
      for (int qr = 0; qr < 2; ++qr) {
        float scl4[4];
#pragma unroll
        for (int reg = 0; reg < 4; ++reg) {
          const int row = q0w + qr*16 + lkg*4 + reg;
          float v0 = (kbase      + lr <= row) ? s[qr][0][reg] : -INFINITY;
          float v1 = (kbase + 16 + lr <= row) ? s[qr][1][reg] : -INFINITY;
          float v2 = (kbase + 32 + lr <= row) ? s[qr][2][reg] : -INFINITY;
          float v3 = (kbase + 48 + lr <= row) ? s[qr][3][reg] : -INFINITY;
          float tm = fmaxf(fmaxf(v0, v1), fmaxf(v2, v3));
          tm = fmaxf(tm, __shfl_xor(tm, 1));
          tm = fmaxf(tm, __shfl_xor(tm, 2));
          tm = fmaxf(tm, __shfl_xor(tm, 4));
          tm = fmaxf(tm, __shfl_xor(tm, 8));
          const float mnew = fmaxf(mrow[qr][reg], tm);
          const float scl  = __expf(mrow[qr][reg] - mnew);
          mrow[qr][reg] = mnew;
          float p0 = __expf(v0 - mnew);
          float p1 = __expf(v1 - mnew);
          float p2 = __expf(v2 - mnew);
          float p3 = __expf(v3 - mnew);
          float rs = (p0 + p1) + (p2 + p3);
          rs += __shfl_xor(rs, 1);
          rs += __shfl_xor(rs, 2);
          rs += __shfl_xor(rs, 4);
          rs += __shfl_xor(rs, 8);
          lrow[qr][reg] = lrow[qr][reg] * scl + rs;
          scl4[reg] = scl;
          const int prow = qr*16 + lkg*4 + reg;
          Ps[wid][prow][lr]      = __float2bfloat16(p0);
          Ps[wid][prow][16 + lr] = __float2bfloat16(p1);
          Ps[wid][prow][32 + lr] = __float2bfloat16(p2);
          Ps[wid][prow][48 + lr] = __float2bfloat16(p3);
        }
#pragma unroll
        for (int db = 0; db < 8; ++db) {
          oacc[qr][db][0] *= scl4[0]; oacc[qr][db][1] *= scl4[1];
          oacc[qr][db][2] *= scl4[2]; oacc[qr][db][3] *= scl4[3];
        }
      }
      asm volatile("s_waitcnt lgkmcnt(0)" ::: "memory");
      __builtin_amdgcn_sched_barrier(0);
      bf16x8 pf[2][2];
#pragma unroll
      for (int qr = 0; qr < 2; ++qr)
#pragma unroll
        for (int k2 = 0; k2 < 2; ++k2)
          pf[qr][k2] = *(const bf16x8*)&Ps[wid][qr*16 + lr][k2*32 + lkg*8];
#pragma unroll
      for (int db = 0; db < 8; ++db) {
        bf16x8 vf0 = *(const bf16x8*)&Vs[db*16 + lr][lkg*8];
        bf16x8 vf1 = *(const bf16x8*)&Vs[db*16 + lr][32 + lkg*8];
#pragma unroll
        for (int qr = 0; qr < 2; ++qr) {
          oacc[qr][db] = mfma16(pf[qr][0], vf0, oacc[qr][db]);
          oacc[qr][db] = mfma16(pf[qr][1], vf1, oacc[qr][db]);
        }
      }
    }
  }

  const int b = bh >> 4, h = bh & 15;
#pragma unroll
  for (int qr = 0; qr < 2; ++qr)
#pragma unroll
    for (int reg = 0; reg < 4; ++reg) {
      const float inv = 1.0f / lrow[qr][reg];
      const int row = q0w + qr*16 + lkg*4 + reg;
      bf16* dst = attnA + ((size_t)(b*LL + row)) * MODEL + h * HDIM;
#pragma unroll
      for (int db = 0; db < 8; ++db)
        dst[db*16 + lr] = __float2bfloat16(oacc[qr][db][reg] * inv);
    }
}

// ---------------- launch ----------------
extern "C" void kernel_launch(void* const* d_in, const int* in_sizes, int n_in,
                              void* d_out, int out_size, void* d_ws, size_t ws_size,
                              hipStream_t stream)
{
  const float* x    = (const float*)d_in[0];
  const float* cosT = (const float*)d_in[1];
  const float* sinT = (const float*)d_in[2];
  const float* Wqkv = (const float*)d_in[3];
  const float* Wc   = (const float*)d_in[4];
  const float* bc   = (const float*)d_in[5];
  float* out = (float*)d_out;

  // workspace layout (bytes):
  //   x16    @ 0         : 16,777,216   (reused as attnA later)
  //   WqkvT  @ 16777216  : 25,165,824
  //   WcT    @ 41943040  :  8,388,608
  //   Qb     @ 50331648  : 16,777,216
  //   Kb     @ 67108864  : 16,777,216
  //   VTb    @ 83886080  : 16,777,216   -> total 100,663,296 B
  if (ws_size < 100663296u) return;
  char* w = (char*)d_ws;
  bf16* x16   = (bf16*)(w);
  bf16* WqkvT = (bf16*)(w + (size_t)16777216);
  bf16* WcT   = (bf16*)(w + (size_t)41943040);
  bf16* Qb    = (bf16*)(w + (size_t)50331648);
  bf16* Kb    = (bf16*)(w + (size_t)67108864);
  bf16* VTb   = (bf16*)(w + (size_t)83886080);
  bf16* attnA = x16;   // overlay: x16 dead after GEMM1

  // allow big dynamic LDS (idempotent; not a stream op -> capture-safe)
  hipFuncSetAttribute(reinterpret_cast<const void*>((&k_gemmP<1,256>)),
                      hipFuncAttributeMaxDynamicSharedMemorySize, 131072);
  hipFuncSetAttribute(reinterpret_cast<const void*>((&k_gemmP<2,128>)),
                      hipFuncAttributeMaxDynamicSharedMemorySize, 98304);

  k_cvt<<<(MTOT*MODEL/4 + 255)/256, 256, 0, stream>>>(x, x16, MTOT*MODEL/4);
  k_transpose<<<dim3(N1/32,    MODEL/32), 256, 0, stream>>>(Wqkv, WqkvT, MODEL, N1);
  k_transpose<<<dim3(MODEL/32, MODEL/32), 256, 0, stream>>>(Wc,   WcT,   MODEL, MODEL);

  k_gemmP<1,256><<<(N1/256)*(MTOT/256), 512, 131072, stream>>>(
      x16, WqkvT, MTOT, N1, MODEL,
      nullptr, nullptr, Qb, Kb, VTb, cosT, sinT);

  k_attn<<<dim3(LL/128, BB*NHEAD), 256, 0, stream>>>(Qb, Kb, VTb, attnA);

  k_gemmP<2,128><<<(MODEL/256)*(MTOT/128), 512, 98304, stream>>>(
      attnA, WcT, MTOT, MODEL, MODEL,
      out, bc, nullptr, nullptr, nullptr, nullptr, nullptr);
}

// Round 9
// 376.686 us; speedup vs baseline: 1.2368x; 1.0308x over previous
//
#include <hip/hip_runtime.h>
#include <hip/hip_bf16.h>

#define MODEL 2048
#define NHEAD 16
#define HDIM  128
#define BB    2
#define LL    2048
#define N1    (3*MODEL)      // 6144
#define MTOT  (BB*LL)        // 4096

typedef __hip_bfloat16 bf16;
typedef __attribute__((ext_vector_type(8))) short bf16x8;
typedef __attribute__((ext_vector_type(4))) float f32x4;

static __device__ __forceinline__ f32x4 mfma16(bf16x8 a, bf16x8 b, f32x4 c) {
  return __builtin_amdgcn_mfma_f32_16x16x32_bf16(a, b, c, 0, 0, 0);
}

// async global->LDS DMA, 16B per lane; LDS base wave-uniform, dest linear
static __device__ __forceinline__ void gl_lds16(const void* g, void* l) {
  __builtin_amdgcn_global_load_lds(
      (const __attribute__((address_space(1))) unsigned int*)g,
      (__attribute__((address_space(3))) unsigned int*)l, 16, 0, 0);
}

// ---------------- prep: f32 -> bf16 (vectorized x4) ----------------
__global__ void k_cvt(const float* __restrict__ in, bf16* __restrict__ out, int n4) {
  int i = blockIdx.x * blockDim.x + threadIdx.x;
  if (i < n4) {
    float4 v = ((const float4*)in)[i];
    bf16* o = out + (size_t)i * 4;
    o[0] = __float2bfloat16(v.x);
    o[1] = __float2bfloat16(v.y);
    o[2] = __float2bfloat16(v.z);
    o[3] = __float2bfloat16(v.w);
  }
}

// ---------------- prep: transpose f32 [R][C] -> bf16 [C][R] ----------------
__global__ __launch_bounds__(256)
void k_transpose(const float* __restrict__ in, bf16* __restrict__ out, int R, int C) {
  __shared__ float t[32][33];
  const int c0 = blockIdx.x * 32, r0 = blockIdx.y * 32;
  const int tx = threadIdx.x & 31;
  const int ty = threadIdx.x >> 5;   // 0..7
#pragma unroll
  for (int i = 0; i < 4; ++i)
    t[ty + 8*i][tx] = in[(size_t)(r0 + ty + 8*i) * C + c0 + tx];
  __syncthreads();
#pragma unroll
  for (int i = 0; i < 4; ++i)
    out[(size_t)(c0 + ty + 8*i) * R + r0 + tx] = __float2bfloat16(t[tx][ty + 8*i]);
}

// ============ 128x128 GEMM, BK=32, 4-buffer pipeline, 2 blocks/CU ============
// C = A[M][K] * BT[N][K]^T. K-tiles of 32 rotate through 4 LDS buffers.
// A [4buf][128][32] @0 (32KB), B same @32768. 64KB total -> 2 blocks/CU:
// cross-BLOCK drift overlaps the LDS-read bursts of one block with the MFMA
// bursts of the other (intra-block lockstep is mandatory: staging is
// distributed across waves, so every tile needs a collective barrier after
// all waves' vmcnt covering it -- the r8 failure mode).
// Schedule per tile (r7-proven): ds_read 6 frags; stage tile t+3 (2 gl_lds);
// lgkm0; 8 MFMA; vmcnt(4) completes tile t+1 (outstanding = t+1..t+3 = 6);
// barrier. Slot swizzle (r6, verified 0-conflict): read 16B-slot =
// lkg ^ ((row>>1)&3); staged via inverse-permuted SOURCE slot
// (l&3)^((l>>3)&3), linear LDS dest.
// EPI==1: RoPE + scatter Q/K row-major + V^T ; EPI==2: bias + f32 out.

#define BARRIER __builtin_amdgcn_s_barrier()
#define SCHED0  __builtin_amdgcn_sched_barrier(0)
#define PRIO1 __builtin_amdgcn_s_setprio(1)
#define PRIO0 __builtin_amdgcn_s_setprio(0)

template<int EPI>
__global__ __launch_bounds__(512, 4)
void k_gemmP(const bf16* __restrict__ A, const bf16* __restrict__ BT,
             int M, int N, int K,
             float* __restrict__ Cout, const float* __restrict__ bias,
             bf16* __restrict__ Qb, bf16* __restrict__ Kb, bf16* __restrict__ VTb,
             const float* __restrict__ cosT, const float* __restrict__ sinT)
{
  constexpr int ABUF = 8192;           // one A tile (128 rows x 64B)
  constexpr int BBUF = 8192;
  constexpr int AREG = 4 * ABUF;       // 32768
  extern __shared__ char smem[];       // 65536 B

  const int tid = threadIdx.x;
  const int wid = tid >> 6, lane = tid & 63;
  const int wm = wid >> 2, wn = wid & 3;       // wave grid 2(M) x 4(N)
  const int lr = lane & 15, lkg = lane >> 4;

  // XCD-aware block mapping: column-major chunked (nwg % 8 == 0)
  const int nby = M >> 7;
  const int qq = ((N >> 7) * nby) >> 3;
  const int lin = (blockIdx.x & 7) * qq + (blockIdx.x >> 3);
  const int m0 = (lin % nby) << 7, n0 = (lin / nby) << 7;

  // staging: wave wid owns 16 rows; source slot carries inverse swizzle
  const int scol = ((lane & 3) ^ ((lane >> 3) & 3)) * 8;   // bf16 elems
  const bf16* Asrc = A  + (size_t)(m0 + wid*16 + (lane >> 2)) * K + scol;
  const bf16* Bsrc = BT + (size_t)(n0 + wid*16 + (lane >> 2)) * K + scol;

  auto stageA = [&](int t) {
    gl_lds16(Asrc + t*32, smem + (t & 3)*ABUF + wid*1024);
  };
  auto stageB = [&](int t) {
    gl_lds16(Bsrc + t*32, smem + AREG + (t & 3)*BBUF + wid*1024);
  };

  // ds_read fragment bases (row = 64B, slot XOR-swizzled by row bits 1-2)
  const int slotX = (lkg ^ ((lr >> 1) & 3)) * 16;
  const int aBase = wm*4096 + lr*64 + slotX;   // rows wm*64 + mf*16 + lr
  const int bBase = wn*2048 + lr*64 + slotX;   // rows wn*32 + nf*16 + lr

  const f32x4 vzero = {0.f, 0.f, 0.f, 0.f};
  f32x4 acc[4][2];
#pragma unroll
  for (int i = 0; i < 4; ++i)
#pragma unroll
    for (int j = 0; j < 2; ++j) acc[i][j] = vzero;

  const int nt = K >> 5;              // K-tiles of 32 (>= 4)

  // prologue: stage tiles 0,1,2 -> wait until tile 0's 2 loads complete
  stageA(0); stageB(0); stageA(1); stageB(1); stageA(2); stageB(2);
  asm volatile("s_waitcnt vmcnt(4)" ::: "memory");
  SCHED0; BARRIER;

  for (int t = 0; t < nt; ++t) {
    const int bufA = (t & 3) * ABUF;
    const int bufB = AREG + (t & 3) * BBUF;
    const int ts   = (t + 3 < nt) ? t + 3 : nt - 1;   // clamp: same-data dup
    bf16x8 aFr[4], bFr[2];

#pragma unroll
    for (int mf = 0; mf < 4; ++mf)
      aFr[mf] = *(const bf16x8*)(smem + bufA + aBase + mf*1024);
#pragma unroll
    for (int nf = 0; nf < 2; ++nf)
      bFr[nf] = *(const bf16x8*)(smem + bufB + bBase + nf*1024);
    stageA(ts); stageB(ts);

    asm volatile("s_waitcnt lgkmcnt(0)" ::: "memory");
    SCHED0;
    PRIO1;
#pragma unroll
    for (int mf = 0; mf < 4; ++mf)
#pragma unroll
      for (int nf = 0; nf < 2; ++nf)
        acc[mf][nf] = mfma16(aFr[mf], bFr[nf], acc[mf][nf]);
    PRIO0;
    // complete tile t+1's loads (outstanding = tiles t+1..t+3 = 6 loads)
    asm volatile("s_waitcnt vmcnt(4)" ::: "memory");
    SCHED0;
    BARRIER;                          // collective: tile t+1 visible to all
  }

  if constexpr (EPI == 1) {
    const float inv_sqrt_d = 0.08838834764831845f;  // 1/sqrt(128)
#pragma unroll
    for (int nf = 0; nf < 2; ++nf) {
      const int gcb = n0 + wn*32 + nf*16;           // wave-uniform, mult of 16
      const int section = gcb >> 11;                // 0=q 1=k 2=v
      const int cc = (gcb & 2047) + lr;
      const int h = cc >> 7, d = cc & 127;
#pragma unroll
      for (int mf = 0; mf < 4; ++mf) {
#pragma unroll
        for (int reg = 0; reg < 4; ++reg) {
          const int grow = m0 + wm*64 + mf*16 + lkg*4 + reg;
          const int bidx = grow >> 11, lseq = grow & 2047;
          float val = acc[mf][nf][reg];
          if (section < 2) {
            float p = __shfl_xor(val, 1);           // RoPE pair partner
            const int fi = d >> 1;
            float cv = cosT[(size_t)lseq * 64 + fi];
            float sv = sinT[(size_t)lseq * 64 + fi];
            float r = (d & 1) ? fmaf(p, sv, val * cv)
                              : fmaf(val, cv, -p * sv);
            if (section == 0) {
              r *= inv_sqrt_d;
              Qb[((size_t)(bidx*NHEAD + h) * LL + lseq) * HDIM + d] = __float2bfloat16(r);
            } else {
              Kb[((size_t)(bidx*NHEAD + h) * LL + lseq) * HDIM + d] = __float2bfloat16(r);
            }
          } else {
            VTb[((size_t)(bidx*NHEAD + h) * HDIM + d) * LL + lseq] = __float2bfloat16(val);
          }
        }
      }
    }
  } else {
#pragma unroll
    for (int nf = 0; nf < 2; ++nf) {
      const int gcol = n0 + wn*32 + nf*16 + lr;
      const float bv = bias[gcol];
#pragma unroll
      for (int mf = 0; mf < 4; ++mf) {
#pragma unroll
        for (int reg = 0; reg < 4; ++reg) {
          const int grow = m0 + wm*64 + mf*16 + lkg*4 + reg;
          Cout[(size_t)grow * N + gcol] = acc[mf][nf][reg] + bv;
        }
      }
    }
  }
}

// ---------------- flash attention: balanced q-tile pairing ----------------
// Block bx handles q-tiles (15-bx) then (bx): per-block KV work is uniform
// (17 tile-units) instead of 2x-spread -> critical path = average, not max.
// Grid 8 x 32 = 256 blocks, 2 blocks/CU, all resident.
__global__ __launch_bounds__(256, 2)
void k_attn(const bf16* __restrict__ Qb, const bf16* __restrict__ Kb,
            const bf16* __restrict__ VTb, bf16* __restrict__ attnA)
{
  __shared__ bf16 Ks[64][136];
  __shared__ bf16 Vs[128][72];
  __shared__ bf16 Ps[4][32][72];

  const int bh  = blockIdx.y;
  const int bx  = blockIdx.x;                 // 0..7
  const int tid = threadIdx.x;
  const int wid = tid >> 6, lane = tid & 63;
  const int lr  = lane & 15, lkg = lane >> 4;

  const bf16* Qh = Qb  + (size_t)bh * LL * HDIM;
  const bf16* Kh = Kb  + (size_t)bh * LL * HDIM;
  const bf16* Vh = VTb + (size_t)bh * HDIM * LL;
  const int b = bh >> 4, h = bh & 15;
  const f32x4 vzero = {0.f, 0.f, 0.f, 0.f};

  for (int pp = 0; pp < 2; ++pp) {
    const int qt  = pp ? bx : (15 - bx);      // heavy tile first
    const int Q0  = qt * 128;
    const int q0w = Q0 + wid * 32;

    bf16x8 qf[2][4];
#pragma unroll
    for (int qr = 0; qr < 2; ++qr)
#pragma unroll
      for (int kk = 0; kk < 4; ++kk)
        qf[qr][kk] = *(const bf16x8*)(Qh + (size_t)(q0w + qr*16 + lr) * HDIM + kk*32 + lkg*8);

    f32x4 oacc[2][8];
#pragma unroll
    for (int qr = 0; qr < 2; ++qr)
#pragma unroll
      for (int db = 0; db < 8; ++db) oacc[qr][db] = vzero;
    float mrow[2][4], lrow[2][4];
#pragma unroll
    for (int qr = 0; qr < 2; ++qr)
#pragma unroll
      for (int r = 0; r < 4; ++r) { mrow[qr][r] = -INFINITY; lrow[qr][r] = 0.f; }

    const int NT = Q0 / 64 + 2;
    bf16x8 kpre[4], vpre[4];
#pragma unroll
    for (int j = 0; j < 4; ++j) {
      const int c = j*256 + tid;
      kpre[j] = *(const bf16x8*)(Kh + (size_t)(c >> 4) * HDIM + (c & 15) * 8);
      vpre[j] = *(const bf16x8*)(Vh + (size_t)(c >> 3) * LL + (c & 7) * 8);
    }

    for (int kt = 0; kt < NT; ++kt) {
      const int kbase = kt * 64;
      __syncthreads();
#pragma unroll
      for (int j = 0; j < 4; ++j) {
        const int c = j*256 + tid;
        *(bf16x8*)&Ks[c >> 4][(c & 15) * 8] = kpre[j];
        *(bf16x8*)&Vs[c >> 3][(c & 7) * 8]  = vpre[j];
      }
      __syncthreads();
      if (kt + 1 < NT) {
#pragma unroll
        for (int j = 0; j < 4; ++j) {
          const int c = j*256 + tid;
          kpre[j] = *(const bf16x8*)(Kh + (size_t)((kt+1)*64 + (c >> 4)) * HDIM + (c & 15) * 8);
          vpre[j] = *(const bf16x8*)(Vh + (size_t)(c >> 3) * LL + (kt+1)*64 + (c & 7) * 8);
        }
      }
      if (kbase <= q0w + 31) {
        f32x4 s[2][4];
#pragma unroll
        for (int qr = 0; qr < 2; ++qr)
#pragma unroll
          for (int c = 0; c < 4; ++c) s[qr][c] = vzero;
#pragma unroll
        for (int c = 0; c < 4; ++c) {
          bf16x8 kf[4];
#pragma unroll
          for (int kk = 0; kk < 4; ++kk)
            kf[kk] = *(const bf16x8*)&Ks[c*16 + lr][kk*32 + lkg*8];
#pragma unroll
          for (int qr = 0; qr < 2; ++qr)
#pragma unroll
            for (int kk = 0; kk < 4; ++kk)
              s[qr][c] = mfma16(qf[qr][kk], kf[kk], s[qr][c]);
        }
#pragma unroll
        for (int qr = 0; qr < 2; ++qr) {
          float scl4[4];
#pragma unroll
          for (int reg = 0; reg < 4; ++reg) {
            const int row = q0w + qr*16 + lkg*4 + reg;
            float v0 = (kbase      + lr <= row) ? s[qr][0][reg] : -INFINITY;
            float v1 = (kbase + 16 + lr <= row) ? s[qr][1][reg] : -INFINITY;
            float v2 = (kbase + 32 + lr <= row) ? s[qr][2][reg] : -INFINITY;
            float v3 = (kbase + 48 + lr <= row) ? s[qr][3][reg] : -INFINITY;
            float tm = fmaxf(fmaxf(v0, v1), fmaxf(v2, v3));
            tm = fmaxf(tm, __shfl_xor(tm, 1));
            tm = fmaxf(tm, __shfl_xor(tm, 2));
            tm = fmaxf(tm, __shfl_xor(tm, 4));
            tm = fmaxf(tm, __shfl_xor(tm, 8));
            const float mnew = fmaxf(mrow[qr][reg], tm);
            const float scl  = __expf(mrow[qr][reg] - mnew);
            mrow[qr][reg] = mnew;
            float p0 = __expf(v0 - mnew);
            float p1 = __expf(v1 - mnew);
            float p2 = __expf(v2 - mnew);
            float p3 = __expf(v3 - mnew);
            float rs = (p0 + p1) + (p2 + p3);
            rs += __shfl_xor(rs, 1);
            rs += __shfl_xor(rs, 2);
            rs += __shfl_xor(rs, 4);
            rs += __shfl_xor(rs, 8);
            lrow[qr][reg] = lrow[qr][reg] * scl + rs;
            scl4[reg] = scl;
            const int prow = qr*16 + lkg*4 + reg;
            Ps[wid][prow][lr]      = __float2bfloat16(p0);
            Ps[wid][prow][16 + lr] = __float2bfloat16(p1);
            Ps[wid][prow][32 + lr] = __float2bfloat16(p2);
            Ps[wid][prow][48 + lr] = __float2bfloat16(p3);
          }
#pragma unroll
          for (int db = 0; db < 8; ++db) {
            oacc[qr][db][0] *= scl4[0]; oacc[qr][db][1] *= scl4[1];
            oacc[qr][db][2] *= scl4[2]; oacc[qr][db][3] *= scl4[3];
          }
        }
        asm volatile("s_waitcnt lgkmcnt(0)" ::: "memory");
        __builtin_amdgcn_sched_barrier(0);
        bf16x8 pf[2][2];
#pragma unroll
        for (int qr = 0; qr < 2; ++qr)
#pragma unroll
          for (int k2 = 0; k2 < 2; ++k2)
            pf[qr][k2] = *(const bf16x8*)&Ps[wid][qr*16 + lr][k2*32 + lkg*8];
#pragma unroll
        for (int db = 0; db < 8; ++db) {
          bf16x8 vf0 = *(const bf16x8*)&Vs[db*16 + lr][lkg*8];
          bf16x8 vf1 = *(const bf16x8*)&Vs[db*16 + lr][32 + lkg*8];
#pragma unroll
          for (int qr = 0; qr < 2; ++qr) {
            oacc[qr][db] = mfma16(pf[qr][0], vf0, oacc[qr][db]);
            oacc[qr][db] = mfma16(pf[qr][1], vf1, oacc[qr][db]);
          }
        }
      }
    }

#pragma unroll
    for (int qr = 0; qr < 2; ++qr)
#pragma unroll
      for (int reg = 0; reg < 4; ++reg) {
        const float inv = 1.0f / lrow[qr][reg];
        const int row = q0w + qr*16 + lkg*4 + reg;
        bf16* dst = attnA + ((size_t)(b*LL + row)) * MODEL + h * HDIM;
#pragma unroll
        for (int db = 0; db < 8; ++db)
          dst[db*16 + lr] = __float2bfloat16(oacc[qr][db][reg] * inv);
      }
  }
}

// ---------------- launch ----------------
extern "C" void kernel_launch(void* const* d_in, const int* in_sizes, int n_in,
                              void* d_out, int out_size, void* d_ws, size_t ws_size,
                              hipStream_t stream)
{
  const float* x    = (const float*)d_in[0];
  const float* cosT = (const float*)d_in[1];
  const float* sinT = (const float*)d_in[2];
  const float* Wqkv = (const float*)d_in[3];
  const float* Wc   = (const float*)d_in[4];
  const float* bc   = (const float*)d_in[5];
  float* out = (float*)d_out;

  // workspace layout (bytes):
  //   x16    @ 0         : 16,777,216   (reused as attnA later)
  //   WqkvT  @ 16777216  : 25,165,824
  //   WcT    @ 41943040  :  8,388,608
  //   Qb     @ 50331648  : 16,777,216
  //   Kb     @ 67108864  : 16,777,216
  //   VTb    @ 83886080  : 16,777,216   -> total 100,663,296 B
  if (ws_size < 100663296u) return;
  char* w = (char*)d_ws;
  bf16* x16   = (bf16*)(w);
  bf16* WqkvT = (bf16*)(w + (size_t)16777216);
  bf16* WcT   = (bf16*)(w + (size_t)41943040);
  bf16* Qb    = (bf16*)(w + (size_t)50331648);
  bf16* Kb    = (bf16*)(w + (size_t)67108864);
  bf16* VTb   = (bf16*)(w + (size_t)83886080);
  bf16* attnA = x16;   // overlay: x16 dead after GEMM1

  // allow 64KB dynamic LDS (idempotent; not a stream op -> capture-safe)
  hipFuncSetAttribute(reinterpret_cast<const void*>(&k_gemmP<1>),
                      hipFuncAttributeMaxDynamicSharedMemorySize, 65536);
  hipFuncSetAttribute(reinterpret_cast<const void*>(&k_gemmP<2>),
                      hipFuncAttributeMaxDynamicSharedMemorySize, 65536);

  k_cvt<<<(MTOT*MODEL/4 + 255)/256, 256, 0, stream>>>(x, x16, MTOT*MODEL/4);
  k_transpose<<<dim3(N1/32,    MODEL/32), 256, 0, stream>>>(Wqkv, WqkvT, MODEL, N1);
  k_transpose<<<dim3(MODEL/32, MODEL/32), 256, 0, stream>>>(Wc,   WcT,   MODEL, MODEL);

  // grid 48*32 = 1536 blocks = 3 exact rounds at 2 blocks/CU
  k_gemmP<1><<<(N1/128)*(MTOT/128), 512, 65536, stream>>>(
      x16, WqkvT, MTOT, N1, MODEL,
      nullptr, nullptr, Qb, Kb, VTb, cosT, sinT);

  k_attn<<<dim3(8, BB*NHEAD), 256, 0, stream>>>(Qb, Kb, VTb, attnA);

  // grid 16*32 = 512 blocks = 1 exact round
  k_gemmP<2><<<(MODEL/128)*(MTOT/128), 512, 65536, stream>>>(
      attnA, WcT, MTOT, MODEL, MODEL,
      out, bc, nullptr, nullptr, nullptr, nullptr, nullptr);
}

// Round 10
// 373.005 us; speedup vs baseline: 1.2490x; 1.0099x over previous
//
#include <hip/hip_runtime.h>
#include <hip/hip_bf16.h>

#define MODEL 2048
#define NHEAD 16
#define HDIM  128
#define BB    2
#define LL    2048
#define N1    (3*MODEL)      // 6144
#define MTOT  (BB*LL)        // 4096

typedef __hip_bfloat16 bf16;
typedef __attribute__((ext_vector_type(8))) short bf16x8;
typedef __attribute__((ext_vector_type(4))) float f32x4;

static __device__ __forceinline__ f32x4 mfma16(bf16x8 a, bf16x8 b, f32x4 c) {
  return __builtin_amdgcn_mfma_f32_16x16x32_bf16(a, b, c, 0, 0, 0);
}

// async global->LDS DMA, 16B per lane; LDS base wave-uniform, dest linear
static __device__ __forceinline__ void gl_lds16(const void* g, void* l) {
  __builtin_amdgcn_global_load_lds(
      (const __attribute__((address_space(1))) unsigned int*)g,
      (__attribute__((address_space(3))) unsigned int*)l, 16, 0, 0);
}

// ---------------- prep: f32 -> bf16 (vectorized x4) ----------------
__global__ void k_cvt(const float* __restrict__ in, bf16* __restrict__ out, int n4) {
  int i = blockIdx.x * blockDim.x + threadIdx.x;
  if (i < n4) {
    float4 v = ((const float4*)in)[i];
    bf16* o = out + (size_t)i * 4;
    o[0] = __float2bfloat16(v.x);
    o[1] = __float2bfloat16(v.y);
    o[2] = __float2bfloat16(v.z);
    o[3] = __float2bfloat16(v.w);
  }
}

// ---------------- prep: transpose f32 [R][C] -> bf16 [C][R] ----------------
__global__ __launch_bounds__(256)
void k_transpose(const float* __restrict__ in, bf16* __restrict__ out, int R, int C) {
  __shared__ float t[32][33];
  const int c0 = blockIdx.x * 32, r0 = blockIdx.y * 32;
  const int tx = threadIdx.x & 31;
  const int ty = threadIdx.x >> 5;   // 0..7
#pragma unroll
  for (int i = 0; i < 4; ++i)
    t[ty + 8*i][tx] = in[(size_t)(r0 + ty + 8*i) * C + c0 + tx];
  __syncthreads();
#pragma unroll
  for (int i = 0; i < 4; ++i)
    out[(size_t)(c0 + ty + 8*i) * R + r0 + tx] = __float2bfloat16(t[tx][ty + 8*i]);
}

// ====== 128x128 GEMM, BK=32, 4-buffer pipeline, 4 waves, 2 blocks/CU ======
// C = A[M][K] * BT[N][K]^T. K-tiles of 32 rotate through 4 LDS buffers.
// A [4buf][128][32] @0 (32KB), B same @32768; 64KB -> 2 blocks/CU.
// r10: 4 waves (grid 2x2, 64x64 output/wave): MFMA/ds_read ratio 2.0 vs 1.33
// -> per-CU LDS pipe 768cy vs MFMA 620cy (balanced); shorter barrier chain.
// Staging: wave owns 32 rows per tile (2 gl_lds per matrix, VMT=4/tile);
// depth-3 (stage t+3 during t); per-wave vmcnt(8) at tile end completes t+1;
// collective barrier per tile makes it visible (staging is distributed -> the
// barrier is mandatory, r8 lesson). Slot swizzle (r6, 0-conflict verified):
// read 16B-slot = lkg ^ ((lr>>1)&3), staged via inverse-permuted SOURCE slot
// (l&3)^((l>>3)&3), linear LDS dest. Counted lgkm(4) starts first 4 MFMAs
// while the back half of the 8 ds_reads drains.
// EPI==1: RoPE + scatter Q/K row-major + V^T ; EPI==2: bias + f32 out.

#define BARRIER __builtin_amdgcn_s_barrier()
#define SCHED0  __builtin_amdgcn_sched_barrier(0)
#define PRIO1 __builtin_amdgcn_s_setprio(1)
#define PRIO0 __builtin_amdgcn_s_setprio(0)

template<int EPI>
__global__ __launch_bounds__(256, 2)
void k_gemmP(const bf16* __restrict__ A, const bf16* __restrict__ BT,
             int M, int N, int K,
             float* __restrict__ Cout, const float* __restrict__ bias,
             bf16* __restrict__ Qb, bf16* __restrict__ Kb, bf16* __restrict__ VTb,
             const float* __restrict__ cosT, const float* __restrict__ sinT)
{
  constexpr int ABUF = 8192;           // one A tile (128 rows x 64B)
  constexpr int BBUF = 8192;
  constexpr int AREG = 4 * ABUF;       // 32768
  extern __shared__ char smem[];       // 65536 B

  const int tid = threadIdx.x;
  const int wid = tid >> 6, lane = tid & 63;
  const int wm = wid >> 1, wn = wid & 1;       // wave grid 2(M) x 2(N)
  const int lr = lane & 15, lkg = lane >> 4;

  // XCD-aware block mapping: column-major chunked (nwg % 8 == 0)
  const int nby = M >> 7;
  const int qq = ((N >> 7) * nby) >> 3;
  const int lin = (blockIdx.x & 7) * qq + (blockIdx.x >> 3);
  const int m0 = (lin % nby) << 7, n0 = (lin / nby) << 7;

  // staging: wave wid owns rows [wid*32, wid*32+32); source slot carries
  // the inverse swizzle; LDS dest linear
  const int scol = ((lane & 3) ^ ((lane >> 3) & 3)) * 8;   // bf16 elems
  const bf16* Asrc = A  + (size_t)(m0 + wid*32 + (lane >> 2)) * K + scol;
  const bf16* Bsrc = BT + (size_t)(n0 + wid*32 + (lane >> 2)) * K + scol;

  auto stageA = [&](int t) {
    const bf16* g = Asrc + t*32;
    char* d = smem + (t & 3)*ABUF + wid*2048;
    gl_lds16(g, d);
    gl_lds16(g + (size_t)16*K, d + 1024);
  };
  auto stageB = [&](int t) {
    const bf16* g = Bsrc + t*32;
    char* d = smem + AREG + (t & 3)*BBUF + wid*2048;
    gl_lds16(g, d);
    gl_lds16(g + (size_t)16*K, d + 1024);
  };

  // ds_read fragment bases (row = 64B, slot XOR-swizzled by row bits 1-2)
  const int slotX = (lkg ^ ((lr >> 1) & 3)) * 16;
  const int aBase = wm*4096 + lr*64 + slotX;   // rows wm*64 + mf*16 + lr
  const int bBase = wn*4096 + lr*64 + slotX;   // rows wn*64 + nf*16 + lr

  const f32x4 vzero = {0.f, 0.f, 0.f, 0.f};
  f32x4 acc[4][4];
#pragma unroll
  for (int i = 0; i < 4; ++i)
#pragma unroll
    for (int j = 0; j < 4; ++j) acc[i][j] = vzero;

  const int nt = K >> 5;              // K-tiles of 32 (>= 4)

  // prologue: stage tiles 0,1,2 (12 loads) -> tile 0 complete at vmcnt(8)
  stageA(0); stageB(0); stageA(1); stageB(1); stageA(2); stageB(2);
  asm volatile("s_waitcnt vmcnt(8)" ::: "memory");
  SCHED0; BARRIER;

  for (int t = 0; t < nt; ++t) {
    const int bufA = (t & 3) * ABUF;
    const int bufB = AREG + (t & 3) * BBUF;
    const int ts   = (t + 3 < nt) ? t + 3 : nt - 1;   // clamp: same-data dup
    bf16x8 aFr[4], bFr[4];

    // issue next-tile staging first (HBM latency starts earliest)
    stageA(ts); stageB(ts);

    // 8 ds_reads: first quad (a0,a1,b0,b1), then back quad
    aFr[0] = *(const bf16x8*)(smem + bufA + aBase);
    aFr[1] = *(const bf16x8*)(smem + bufA + aBase + 1024);
    bFr[0] = *(const bf16x8*)(smem + bufB + bBase);
    bFr[1] = *(const bf16x8*)(smem + bufB + bBase + 1024);
    aFr[2] = *(const bf16x8*)(smem + bufA + aBase + 2048);
    aFr[3] = *(const bf16x8*)(smem + bufA + aBase + 3072);
    bFr[2] = *(const bf16x8*)(smem + bufB + bBase + 2048);
    bFr[3] = *(const bf16x8*)(smem + bufB + bBase + 3072);

    asm volatile("s_waitcnt lgkmcnt(4)" ::: "memory");
    SCHED0;
    PRIO1;
    acc[0][0] = mfma16(aFr[0], bFr[0], acc[0][0]);
    acc[0][1] = mfma16(aFr[0], bFr[1], acc[0][1]);
    acc[1][0] = mfma16(aFr[1], bFr[0], acc[1][0]);
    acc[1][1] = mfma16(aFr[1], bFr[1], acc[1][1]);
    asm volatile("s_waitcnt lgkmcnt(0)" ::: "memory");
    SCHED0;
#pragma unroll
    for (int mf = 0; mf < 4; ++mf)
#pragma unroll
      for (int nf = 0; nf < 4; ++nf)
        if (mf >= 2 || nf >= 2)
          acc[mf][nf] = mfma16(aFr[mf], bFr[nf], acc[mf][nf]);
    PRIO0;
    // complete tile t+1's loads (outstanding = stages for t+1..t+3 = 12)
    asm volatile("s_waitcnt vmcnt(8)" ::: "memory");
    SCHED0;
    BARRIER;                          // collective: tile t+1 visible to all
  }

  if constexpr (EPI == 1) {
    const float inv_sqrt_d = 0.08838834764831845f;  // 1/sqrt(128)
#pragma unroll
    for (int nf = 0; nf < 4; ++nf) {
      const int gcb = n0 + wn*64 + nf*16;           // wave-uniform, mult of 16
      const int section = gcb >> 11;                // 0=q 1=k 2=v
      const int cc = (gcb & 2047) + lr;
      const int h = cc >> 7, d = cc & 127;
#pragma unroll
      for (int mf = 0; mf < 4; ++mf) {
#pragma unroll
        for (int reg = 0; reg < 4; ++reg) {
          const int grow = m0 + wm*64 + mf*16 + lkg*4 + reg;
          const int bidx = grow >> 11, lseq = grow & 2047;
          float val = acc[mf][nf][reg];
          if (section < 2) {
            float p = __shfl_xor(val, 1);           // RoPE pair partner
            const int fi = d >> 1;
            float cv = cosT[(size_t)lseq * 64 + fi];
            float sv = sinT[(size_t)lseq * 64 + fi];
            float r = (d & 1) ? fmaf(p, sv, val * cv)
                              : fmaf(val, cv, -p * sv);
            if (section == 0) {
              r *= inv_sqrt_d;
              Qb[((size_t)(bidx*NHEAD + h) * LL + lseq) * HDIM + d] = __float2bfloat16(r);
            } else {
              Kb[((size_t)(bidx*NHEAD + h) * LL + lseq) * HDIM + d] = __float2bfloat16(r);
            }
          } else {
            VTb[((size_t)(bidx*NHEAD + h) * HDIM + d) * LL + lseq] = __float2bfloat16(val);
          }
        }
      }
    }
  } else {
#pragma unroll
    for (int nf = 0; nf < 4; ++nf) {
      const int gcol = n0 + wn*64 + nf*16 + lr;
      const float bv = bias[gcol];
#pragma unroll
      for (int mf = 0; mf < 4; ++mf) {
#pragma unroll
        for (int reg = 0; reg < 4; ++reg) {
          const int grow = m0 + wm*64 + mf*16 + lkg*4 + reg;
          Cout[(size_t)grow * N + gcol] = acc[mf][nf][reg] + bv;
        }
      }
    }
  }
}

// ---------------- flash attention: balanced q-tile pairing (r9) ----------------
__global__ __launch_bounds__(256, 2)
void k_attn(const bf16* __restrict__ Qb, const bf16* __restrict__ Kb,
            const bf16* __restrict__ VTb, bf16* __restrict__ attnA)
{
  __shared__ bf16 Ks[64][136];
  __shared__ bf16 Vs[128][72];
  __shared__ bf16 Ps[4][32][72];

  const int bh  = blockIdx.y;
  const int bx  = blockIdx.x;                 // 0..7
  const int tid = threadIdx.x;
  const int wid = tid >> 6, lane = tid & 63;
  const int lr  = lane & 15, lkg = lane >> 4;

  const bf16* Qh = Qb  + (size_t)bh * LL * HDIM;
  const bf16* Kh = Kb  + (size_t)bh * LL * HDIM;
  const bf16* Vh = VTb + (size_t)bh * HDIM * LL;
  const int b = bh >> 4, h = bh & 15;
  const f32x4 vzero = {0.f, 0.f, 0.f, 0.f};

  for (int pp = 0; pp < 2; ++pp) {
    const int qt  = pp ? bx : (15 - bx);      // heavy tile first
    const int Q0  = qt * 128;
    const int q0w = Q0 + wid * 32;

    bf16x8 qf[2][4];
#pragma unroll
    for (int qr = 0; qr < 2; ++qr)
#pragma unroll
      for (int kk = 0; kk < 4; ++kk)
        qf[qr][kk] = *(const bf16x8*)(Qh + (size_t)(q0w + qr*16 + lr) * HDIM + kk*32 + lkg*8);

    f32x4 oacc[2][8];
#pragma unroll
    for (int qr = 0; qr < 2; ++qr)
#pragma unroll
      for (int db = 0; db < 8; ++db) oacc[qr][db] = vzero;
    float mrow[2][4], lrow[2][4];
#pragma unroll
    for (int qr = 0; qr < 2; ++qr)
#pragma unroll
      for (int r = 0; r < 4; ++r) { mrow[qr][r] = -INFINITY; lrow[qr][r] = 0.f; }

    const int NT = Q0 / 64 + 2;
    bf16x8 kpre[4], vpre[4];
#pragma unroll
    for (int j = 0; j < 4; ++j) {
      const int c = j*256 + tid;
      kpre[j] = *(const bf16x8*)(Kh + (size_t)(c >> 4) * HDIM + (c & 15) * 8);
      vpre[j] = *(const bf16x8*)(Vh + (size_t)(c >> 3) * LL + (c & 7) * 8);
    }

    for (int kt = 0; kt < NT; ++kt) {
      const int kbase = kt * 64;
      __syncthreads();
#pragma unroll
      for (int j = 0; j < 4; ++j) {
        const int c = j*256 + tid;
        *(bf16x8*)&Ks[c >> 4][(c & 15) * 8] = kpre[j];
        *(bf16x8*)&Vs[c >> 3][(c & 7) * 8]  = vpre[j];
      }
      __syncthreads();
      if (kt + 1 < NT) {
#pragma unroll
        for (int j = 0; j < 4; ++j) {
          const int c = j*256 + tid;
          kpre[j] = *(const bf16x8*)(Kh + (size_t)((kt+1)*64 + (c >> 4)) * HDIM + (c & 15) * 8);
          vpre[j] = *(const bf16x8*)(Vh + (size_t)(c >> 3) * LL + (kt+1)*64 + (c & 7) * 8);
        }
      }
      if (kbase <= q0w + 31) {
        f32x4 s[2][4];
#pragma unroll
        for (int qr = 0; qr < 2; ++qr)
#pragma unroll
          for (int c = 0; c < 4; ++c) s[qr][c] = vzero;
#pragma unroll
        for (int c = 0; c < 4; ++c) {
          bf16x8 kf[4];
#pragma unroll
          for (int kk = 0; kk < 4; ++kk)
            kf[kk] = *(const bf16x8*)&Ks[c*16 + lr][kk*32 + lkg*8];
#pragma unroll
          for (int qr = 0; qr < 2; ++qr)
#pragma unroll
            for (int kk = 0; kk < 4; ++kk)
              s[qr][c] = mfma16(qf[qr][kk], kf[kk], s[qr][c]);
        }
#pragma unroll
        for (int qr = 0; qr < 2; ++qr) {
          float scl4[4];
#pragma unroll
          for (int reg = 0; reg < 4; ++reg) {
            const int row = q0w + qr*16 + lkg*4 + reg;
            float v0 = (kbase      + lr <= row) ? s[qr][0][reg] : -INFINITY;
            float v1 = (kbase + 16 + lr <= row) ? s[qr][1][reg] : -INFINITY;
            float v2 = (kbase + 32 + lr <= row) ? s[qr][2][reg] : -INFINITY;
            float v3 = (kbase + 48 + lr <= row) ? s[qr][3][reg] : -INFINITY;
            float tm = fmaxf(fmaxf(v0, v1), fmaxf(v2, v3));
            tm = fmaxf(tm, __shfl_xor(tm, 1));
            tm = fmaxf(tm, __shfl_xor(tm, 2));
            tm = fmaxf(tm, __shfl_xor(tm, 4));
            tm = fmaxf(tm, __shfl_xor(tm, 8));
            const float mnew = fmaxf(mrow[qr][reg], tm);
            const float scl  = __expf(mrow[qr][reg] - mnew);
            mrow[qr][reg] = mnew;
            float p0 = __expf(v0 - mnew);
            float p1 = __expf(v1 - mnew);
            float p2 = __expf(v2 - mnew);
            float p3 = __expf(v3 - mnew);
            float rs = (p0 + p1) + (p2 + p3);
            rs += __shfl_xor(rs, 1);
            rs += __shfl_xor(rs, 2);
            rs += __shfl_xor(rs, 4);
            rs += __shfl_xor(rs, 8);
            lrow[qr][reg] = lrow[qr][reg] * scl + rs;
            scl4[reg] = scl;
            const int prow = qr*16 + lkg*4 + reg;
            Ps[wid][prow][lr]      = __float2bfloat16(p0);
            Ps[wid][prow][16 + lr] = __float2bfloat16(p1);
            Ps[wid][prow][32 + lr] = __float2bfloat16(p2);
            Ps[wid][prow][48 + lr] = __float2bfloat16(p3);
          }
#pragma unroll
          for (int db = 0; db < 8; ++db) {
            oacc[qr][db][0] *= scl4[0]; oacc[qr][db][1] *= scl4[1];
            oacc[qr][db][2] *= scl4[2]; oacc[qr][db][3] *= scl4[3];
          }
        }
        asm volatile("s_waitcnt lgkmcnt(0)" ::: "memory");
        __builtin_amdgcn_sched_barrier(0);
        bf16x8 pf[2][2];
#pragma unroll
        for (int qr = 0; qr < 2; ++qr)
#pragma unroll
          for (int k2 = 0; k2 < 2; ++k2)
            pf[qr][k2] = *(const bf16x8*)&Ps[wid][qr*16 + lr][k2*32 + lkg*8];
#pragma unroll
        for (int db = 0; db < 8; ++db) {
          bf16x8 vf0 = *(const bf16x8*)&Vs[db*16 + lr][lkg*8];
          bf16x8 vf1 = *(const bf16x8*)&Vs[db*16 + lr][32 + lkg*8];
#pragma unroll
          for (int qr = 0; qr < 2; ++qr) {
            oacc[qr][db] = mfma16(pf[qr][0], vf0, oacc[qr][db]);
            oacc[qr][db] = mfma16(pf[qr][1], vf1, oacc[qr][db]);
          }
        }
      }
    }

#pragma unroll
    for (int qr = 0; qr < 2; ++qr)
#pragma unroll
      for (int reg = 0; reg < 4; ++reg) {
        const float inv = 1.0f / lrow[qr][reg];
        const int row = q0w + qr*16 + lkg*4 + reg;
        bf16* dst = attnA + ((size_t)(b*LL + row)) * MODEL + h * HDIM;
#pragma unroll
        for (int db = 0; db < 8; ++db)
          dst[db*16 + lr] = __float2bfloat16(oacc[qr][db][reg] * inv);
      }
  }
}

// ---------------- launch ----------------
extern "C" void kernel_launch(void* const* d_in, const int* in_sizes, int n_in,
                              void* d_out, int out_size, void* d_ws, size_t ws_size,
                              hipStream_t stream)
{
  const float* x    = (const float*)d_in[0];
  const float* cosT = (const float*)d_in[1];
  const float* sinT = (const float*)d_in[2];
  const float* Wqkv = (const float*)d_in[3];
  const float* Wc   = (const float*)d_in[4];
  const float* bc   = (const float*)d_in[5];
  float* out = (float*)d_out;

  // workspace layout (bytes):
  //   x16    @ 0         : 16,777,216   (reused as attnA later)
  //   WqkvT  @ 16777216  : 25,165,824
  //   WcT    @ 41943040  :  8,388,608
  //   Qb     @ 50331648  : 16,777,216
  //   Kb     @ 67108864  : 16,777,216
  //   VTb    @ 83886080  : 16,777,216   -> total 100,663,296 B
  if (ws_size < 100663296u) return;
  char* w = (char*)d_ws;
  bf16* x16   = (bf16*)(w);
  bf16* WqkvT = (bf16*)(w + (size_t)16777216);
  bf16* WcT   = (bf16*)(w + (size_t)41943040);
  bf16* Qb    = (bf16*)(w + (size_t)50331648);
  bf16* Kb    = (bf16*)(w + (size_t)67108864);
  bf16* VTb   = (bf16*)(w + (size_t)83886080);
  bf16* attnA = x16;   // overlay: x16 dead after GEMM1

  // allow 64KB dynamic LDS (idempotent; not a stream op -> capture-safe)
  hipFuncSetAttribute(reinterpret_cast<const void*>(&k_gemmP<1>),
                      hipFuncAttributeMaxDynamicSharedMemorySize, 65536);
  hipFuncSetAttribute(reinterpret_cast<const void*>(&k_gemmP<2>),
                      hipFuncAttributeMaxDynamicSharedMemorySize, 65536);

  k_cvt<<<(MTOT*MODEL/4 + 255)/256, 256, 0, stream>>>(x, x16, MTOT*MODEL/4);
  k_transpose<<<dim3(N1/32,    MODEL/32), 256, 0, stream>>>(Wqkv, WqkvT, MODEL, N1);
  k_transpose<<<dim3(MODEL/32, MODEL/32), 256, 0, stream>>>(Wc,   WcT,   MODEL, MODEL);

  // grid 48*32 = 1536 blocks (2 blocks/CU -> 3 exact rounds)
  k_gemmP<1><<<(N1/128)*(MTOT/128), 256, 65536, stream>>>(
      x16, WqkvT, MTOT, N1, MODEL,
      nullptr, nullptr, Qb, Kb, VTb, cosT, sinT);

  k_attn<<<dim3(8, BB*NHEAD), 256, 0, stream>>>(Qb, Kb, VTb, attnA);

  // grid 16*32 = 512 blocks = 1 exact round
  k_gemmP<2><<<(MODEL/128)*(MTOT/128), 256, 65536, stream>>>(
      attnA, WcT, MTOT, MODEL, MODEL,
      out, bc, nullptr, nullptr, nullptr, nullptr, nullptr);
}